// Round 15
// baseline (2800.143 us; speedup 1.0000x reference)
//
#include <hip/hip_runtime.h>
#include <hip/hip_bf16.h>
#include <cstdint>
#include <cstddef>

#define TB 4
#define TS 2048
#define TD 768
#define TH 12
#define THD 64
#define TL 6
#define TV 32000
#define TFF 3072
#define TT (TB*TS)   // 8192 tokens
#define TQKV 2304    // fused QKV width

typedef __bf16 bf16_t;
typedef __attribute__((ext_vector_type(8))) __bf16 bf16x8;
typedef __attribute__((ext_vector_type(4))) __bf16 bf16x4;
typedef __attribute__((ext_vector_type(4))) float f32x4;

__device__ __forceinline__ unsigned short f2bf(float f) {
  union { float f; unsigned u; } x; x.f = f;
  unsigned r = x.u + 0x7fffu + ((x.u >> 16) & 1u);
  return (unsigned short)(r >> 16);
}
__device__ __forceinline__ float bf2f(unsigned short u) {
  union { unsigned u; float f; } x; x.u = (unsigned)u << 16; return x.f;
}

// v_exp_f32 computes 2^x natively
__device__ __forceinline__ float fexp2(float x) {
  float r; asm("v_exp_f32 %0, %1" : "=v"(r) : "v"(x)); return r;
}

// async global->LDS, 16B per lane. lds base must be wave-uniform.
__device__ __forceinline__ void gld_lds16(const void* g, void* l) {
  unsigned loff = (unsigned)(uintptr_t)l;
  __builtin_amdgcn_global_load_lds(
      (const __attribute__((address_space(1))) unsigned int*)(uintptr_t)g,
      (__attribute__((address_space(3))) unsigned int*)(uintptr_t)loff, 16, 0, 0);
}

#define IRFENCE() asm volatile("" ::: "memory")

// ---------------- embedding gather + RoPE (fp32) ----------------
__global__ void embed_rope(const int* __restrict__ ids, const float* __restrict__ emb,
                           float* __restrict__ h) {
  int t = blockIdx.x;
  int s = t & (TS - 1);
  int id = ids[t];
  const float* row = emb + (size_t)id * TD;
  float* out = h + (size_t)t * TD;
  for (int p = threadIdx.x; p < TD/2; p += blockDim.x) {
    float xe = row[2*p], xo = row[2*p+1];
    float inv = expf(-(float)(2*p) * (9.210340371976184f / (float)TD)); // 10000^{-2p/D}
    float ang = (float)s * inv;
    float c = cosf(ang), sn = sinf(ang);
    out[2*p]   = xe*c - xo*sn;
    out[2*p+1] = xo*c + xe*sn;
  }
}

// ---------------- LayerNorm fp32 -> bf16 (float4 loads, G13) ----------------
__global__ __launch_bounds__(256) void ln_fwd(const float* __restrict__ x,
                                              const float* __restrict__ w,
                                              const float* __restrict__ b,
                                              unsigned short* __restrict__ y) {
  int row = blockIdx.x;
  const float* xr = x + (size_t)row * TD;
  int tid = threadIdx.x;
  float4 v = {0.f, 0.f, 0.f, 0.f};
  if (tid < 192) v = *(const float4*)(xr + tid*4);
  float s = (v.x+v.y)+(v.z+v.w);
  float q = (v.x*v.x+v.y*v.y)+(v.z*v.z+v.w*v.w);
  for (int o = 32; o; o >>= 1) { s += __shfl_down(s, o); q += __shfl_down(q, o); }
  __shared__ float ss[4], sq[4];
  int wave = tid >> 6, lane = tid & 63;
  if (lane == 0) { ss[wave] = s; sq[wave] = q; }
  __syncthreads();
  s = ss[0]+ss[1]+ss[2]+ss[3];
  q = sq[0]+sq[1]+sq[2]+sq[3];
  float mean = s * (1.0f/TD);
  float var  = q * (1.0f/TD) - mean*mean;
  float rstd = rsqrtf(var + 1e-5f);
  if (tid < 192) {
    const float4 wv = *(const float4*)(w + tid*4);
    const float4 bv = *(const float4*)(b + tid*4);
    ushort4 o4;
    o4.x = f2bf((v.x-mean)*rstd*wv.x + bv.x);
    o4.y = f2bf((v.y-mean)*rstd*wv.y + bv.y);
    o4.z = f2bf((v.z-mean)*rstd*wv.z + bv.z);
    o4.w = f2bf((v.w-mean)*rstd*wv.w + bv.w);
    *(ushort4*)(y + (size_t)row*TD + tid*4) = o4;
  }
}

// ---------------- fused: h += Sum(NPART bf16 partials) [+ pbias]; y = LN(h) ----------------
template<int NPART>
__global__ __launch_bounds__(256) void ln_fused(
    float* __restrict__ hbuf, const unsigned short* __restrict__ parts,
    const float* __restrict__ pbias,
    const float* __restrict__ w, const float* __restrict__ b,
    unsigned short* __restrict__ y) {
  int row = blockIdx.x;
  int tid = threadIdx.x;
  float4 v = {0.f, 0.f, 0.f, 0.f};
  if (tid < 192) {
    v = *(const float4*)(hbuf + (size_t)row*TD + tid*4);
    #pragma unroll
    for (int p = 0; p < NPART; ++p) {
      ushort4 u = *(const ushort4*)(parts + (size_t)p*TT*TD + (size_t)row*TD + tid*4);
      v.x += bf2f(u.x); v.y += bf2f(u.y); v.z += bf2f(u.z); v.w += bf2f(u.w);
    }
    if (pbias) {
      float4 pb = *(const float4*)(pbias + tid*4);
      v.x += pb.x; v.y += pb.y; v.z += pb.z; v.w += pb.w;
    }
  }
  float s = (v.x+v.y)+(v.z+v.w);
  float q = (v.x*v.x+v.y*v.y)+(v.z*v.z+v.w*v.w);
  for (int o = 32; o; o >>= 1) { s += __shfl_down(s, o); q += __shfl_down(q, o); }
  __shared__ float ss[4], sq[4];
  int wave = tid >> 6, lane = tid & 63;
  if (lane == 0) { ss[wave] = s; sq[wave] = q; }
  __syncthreads();
  s = ss[0]+ss[1]+ss[2]+ss[3];
  q = sq[0]+sq[1]+sq[2]+sq[3];
  float mean = s * (1.0f/TD);
  float var  = q * (1.0f/TD) - mean*mean;
  float rstd = rsqrtf(var + 1e-5f);
  if (tid < 192) {
    *(float4*)(hbuf + (size_t)row*TD + tid*4) = v;   // updated residual stream
    const float4 wv = *(const float4*)(w + tid*4);
    const float4 bv = *(const float4*)(b + tid*4);
    ushort4 o4;
    o4.x = f2bf((v.x-mean)*rstd*wv.x + bv.x);
    o4.y = f2bf((v.y-mean)*rstd*wv.y + bv.y);
    o4.z = f2bf((v.z-mean)*rstd*wv.z + bv.z);
    o4.w = f2bf((v.w-mean)*rstd*wv.w + bv.w);
    *(ushort4*)(y + (size_t)row*TD + tid*4) = o4;
  }
}

// ---------------- weight transpose (K x N fp32) -> (N x K bf16) ----------------
__global__ __launch_bounds__(256) void transpose_to_bf16(const float* __restrict__ W,
                                                         unsigned short* __restrict__ Wt,
                                                         int K, int N, int row_off,
                                                         size_t lstride) {
  int ntn = N / 64;
  int tk = (blockIdx.x / ntn) * 64;
  int tn = (blockIdx.x % ntn) * 64;
  const float* Wb = W + (size_t)blockIdx.y * K * N;
  unsigned short* Ob = Wt + (size_t)blockIdx.y * lstride;
  __shared__ float tile[64][65];
  int tid = threadIdx.x;
  int c = tid & 63, w = tid >> 6;
  #pragma unroll
  for (int i = 0; i < 16; ++i) {
    int r = i*4 + w;
    tile[r][c] = Wb[(size_t)(tk + r) * N + tn + c];
  }
  __syncthreads();
  #pragma unroll
  for (int i = 0; i < 16; ++i) {
    int r = i*4 + w;
    Ob[(size_t)(row_off + tn + r) * K + tk + c] = f2bf(tile[c][r]);
  }
}

// ---------------- pack q/k/v biases into one [L][2304] buffer ----------------
__global__ void pack_qkv_bias(const float* __restrict__ qb, const float* __restrict__ kb,
                              const float* __restrict__ vb, float* __restrict__ out) {
  int lay = blockIdx.x, i = threadIdx.x;
  out[lay*TQKV + i]        = qb[lay*TD + i];
  out[lay*TQKV + TD + i]   = kb[lay*TD + i];
  out[lay*TQKV + 2*TD + i] = vb[lay*TD + i];
}

// ---------------- fp32 -> bf16 convert (emb) ----------------
__global__ void convert_bf16_k(const float* __restrict__ in, unsigned short* __restrict__ out) {
  size_t i = ((size_t)blockIdx.x * 256 + threadIdx.x) * 4;
  float4 v = *(const float4*)(in + i);
  ushort4 o;
  o.x = f2bf(v.x); o.y = f2bf(v.y); o.z = f2bf(v.z); o.w = f2bf(v.w);
  *(ushort4*)(out + i) = o;
}

// ---------------- 128^2 GEMM v2: 2-phase double-buffer, counted vmcnt, T2 swizzle ----
// MODE 0: bf16 out + bias. 1: + fast GELU. 2: fp32 +=. 3: fp32 =.
// MODE 4: QKV fused — Q/K cols -> out, V cols -> out2 transposed vt[bh][d][s].
// MODE 5: split-K — gridDim.y = #slices; bf16 partial (no bias).
template<int MODE>
__global__ __launch_bounds__(256, 2) void gemm_bt(
    const bf16_t* __restrict__ A, const bf16_t* __restrict__ Bt,
    const float* __restrict__ bias, void* __restrict__ out,
    void* __restrict__ out2,
    int N, int K, int ntn) {
  __shared__ __align__(16) bf16_t As[2][128*64];
  __shared__ __align__(16) bf16_t Bs[2][128*64];
  const int tid = threadIdx.x;
  const int lane = tid & 63;
  const int wave = tid >> 6;
  const int wm = wave >> 1, wn = wave & 1;
  const int nwg = gridDim.x;
  const int orig = blockIdx.x;
  const int qd = nwg >> 3, rr = nwg & 7;
  const int xcd = orig & 7, sub = orig >> 3;
  const int wg = (xcd < rr ? xcd*(qd+1) : rr*(qd+1) + (xcd-rr)*qd) + sub;
  const int tm = wg / ntn, tn = wg % ntn;
  const int nslice = (MODE == 5) ? gridDim.y : 1;
  const int ks = (MODE == 5) ? blockIdx.y : 0;
  const int koff = ks * (K / nslice);
  const bf16_t* Ab = A + (size_t)tm * 128 * K + koff;
  const bf16_t* Bb = Bt + (size_t)tn * 128 * K + koff;
  const int lr = lane >> 3;                  // 0..7 (row within 8-row stage group)
  const int lc = ((lane & 7) ^ lr) * 8;      // pre-swizzled source col (elements)
  const int l15 = lane & 15, l4 = lane >> 4;
  const int flip = (l15 & 7) << 3;           // read-side swizzle (elements)
  const int NT = K / (64 * nslice);
  f32x4 acc[4][4] = {};

#define STAGE(t, buf) do {                                                   \
    _Pragma("unroll")                                                        \
    for (int it = 0; it < 4; ++it) {                                         \
      const int r0 = it*32 + wave*8;                                         \
      gld_lds16(Ab + (size_t)(r0 + lr)*K + (t)*64 + lc, &As[buf][r0*64 + lr*64]); \
      gld_lds16(Bb + (size_t)(r0 + lr)*K + (t)*64 + lc, &Bs[buf][r0*64 + lr*64]); \
    }                                                                        \
  } while (0)

  STAGE(0, 0);
  for (int t = 0; t < NT; ++t) {
    const int cur = t & 1;
    if (t < NT - 1) {
      STAGE(t+1, cur^1);
      asm volatile("s_waitcnt vmcnt(8)" ::: "memory");   // tile-t loads resident
    } else {
      asm volatile("s_waitcnt vmcnt(0)" ::: "memory");
    }
    IRFENCE(); __builtin_amdgcn_s_barrier(); IRFENCE();
    #pragma unroll
    for (int kh = 0; kh < 2; ++kh) {
      bf16x8 af[4], bfr[4];
      #pragma unroll
      for (int i = 0; i < 4; ++i)
        af[i] = *(const bf16x8*)&As[cur][(wm*64 + i*16 + l15)*64 + ((kh*32 + l4*8) ^ flip)];
      #pragma unroll
      for (int i = 0; i < 4; ++i)
        bfr[i] = *(const bf16x8*)&Bs[cur][(wn*64 + i*16 + l15)*64 + ((kh*32 + l4*8) ^ flip)];
      #pragma unroll
      for (int mi = 0; mi < 4; ++mi)
        #pragma unroll
        for (int ni = 0; ni < 4; ++ni)
          acc[mi][ni] = __builtin_amdgcn_mfma_f32_16x16x32_bf16(af[mi], bfr[ni], acc[mi][ni], 0, 0, 0);
    }
    IRFENCE(); __builtin_amdgcn_s_barrier(); IRFENCE();  // all reads of cur done before overwrite
  }
#undef STAGE
  const int rb = tm*128 + wm*64 + l4*4;
  const int cbase = tn*128 + wn*64 + l15;
  const bool vsec = (MODE == 4) && (tn >= (2*TD)/128);   // block-uniform
  #pragma unroll
  for (int mi = 0; mi < 4; ++mi) {
    #pragma unroll
    for (int ni = 0; ni < 4; ++ni) {
      const int c = cbase + ni*16;
      const float bv = (MODE == 3 || MODE == 5) ? 0.0f : bias[c];
      if (MODE == 4 && vsec) {
        // V section: write transposed to vt[bh][d][s], 4 rows -> 4 consecutive s
        const int cc = c - 2*TD;
        const int hh = cc >> 6, d = cc & 63;
        const int row0 = rb + mi*16;
        const int bidx = row0 >> 11, s = row0 & (TS-1);
        ushort4 o4;
        o4.x = f2bf(acc[mi][ni][0] + bv);
        o4.y = f2bf(acc[mi][ni][1] + bv);
        o4.z = f2bf(acc[mi][ni][2] + bv);
        o4.w = f2bf(acc[mi][ni][3] + bv);
        *(ushort4*)((unsigned short*)out2 + ((size_t)(bidx*TH + hh)*THD + d)*TS + s) = o4;
        continue;
      }
      #pragma unroll
      for (int r = 0; r < 4; ++r) {
        const size_t idx = (size_t)(rb + mi*16 + r) * N + c;
        float vv = acc[mi][ni][r] + bv;
        if (MODE == 0 || MODE == 4) {
          ((unsigned short*)out)[idx] = f2bf(vv);
        } else if (MODE == 1) {
          // fast GELU (tanh form): x * e/(1+e), e = 2^(x*(2.3022102+0.102944*x^2))
          float z = vv * (2.3022102f + 0.102944f * vv * vv);
          z = fminf(z, 30.0f);
          float e = fexp2(z);
          vv = vv * e / (1.0f + e);
          ((unsigned short*)out)[idx] = f2bf(vv);
        } else if (MODE == 2) {
          ((float*)out)[idx] += vv;
        } else if (MODE == 5) {
          ((unsigned short*)out)[(size_t)ks*TT*TD + idx] = f2bf(vv);
        } else {
          ((float*)out)[idx] = vv;
        }
      }
    }
  }
}

// ---------------- 256^2 deep-pipelined GEMM (logits only: grid 4000) ----------------
// P3's WAITV(4) is REQUIRED: it establishes A0,B0(t+1) residency before iteration
// t+1's P0 ds_reads (which execute BEFORE P0's own vmcnt wait in program order).
__device__ __forceinline__ int lds_half_off(int R, int C) {
  int lin = ((((R >> 4) << 1) | (C >> 5)) << 10) | ((R & 15) << 6) | ((C & 31) << 1);
  return lin ^ (((R >> 3) & 1) << 5);
}

template<int MODE>
__global__ __launch_bounds__(512, 2) void gemm256(
    const bf16_t* __restrict__ A, const bf16_t* __restrict__ Bt,
    const float* __restrict__ bias, void* __restrict__ out,
    int N, int K, int ntn) {
  __shared__ __align__(16) bf16_t lds[2][2][2][8192];  // [buf][mat][half][16KB]
  const int tid = threadIdx.x;
  const int lane = tid & 63;
  const int wave = tid >> 6;        // 0..7
  const int wm = wave >> 2;         // 0..1
  const int wn = wave & 3;          // 0..3
  const int orig = blockIdx.x;
  const int grp = orig >> 8;        // 8-tn group (ragged tail ok)
  const int rem = orig & 255;
  const int tn = grp*8 + (rem >> 5);
  const int tm = rem & 31;
  const bf16_t* Ab = A  + (size_t)tm * 256 * K;
  const bf16_t* Bb = Bt + (size_t)tn * 256 * K;
  const int l15 = lane & 15, l4 = lane >> 4;
  const int s_row = wave*16 + (lane >> 2);
  const int s_col0 = ((lane & 3) * 8) ^ ((lane >= 32) ? 16 : 0);
  const int NT = K >> 6;

  f32x4 acc[2][4][2][2] = {};
  bf16x8 afr[4][2], bfr0[2][2], bfr1[2][2];

#define STAGEH(mat, half, kt, buf) do {                                          \
    const bf16_t* base_ = (mat) ? Bb : Ab;                                       \
    _Pragma("unroll")                                                            \
    for (int j_ = 0; j_ < 2; ++j_)                                               \
      gld_lds16(base_ + (size_t)((half)*128 + s_row)*K + (kt)*64 + j_*32 + s_col0, \
                &lds[buf][mat][half][(wave*2 + j_) * 512]);                      \
  } while (0)
#define RDA(buf, half) do {                                                      \
    _Pragma("unroll")                                                            \
    for (int m4_ = 0; m4_ < 4; ++m4_)                                            \
      _Pragma("unroll")                                                          \
      for (int kh_ = 0; kh_ < 2; ++kh_)                                          \
        afr[m4_][kh_] = *(const bf16x8*)((const char*)&lds[buf][0][half][0] +    \
            lds_half_off(wm*64 + m4_*16 + l15, kh_*32 + l4*8));                  \
  } while (0)
#define RDB(buf, half, dst) do {                                                 \
    _Pragma("unroll")                                                            \
    for (int n2_ = 0; n2_ < 2; ++n2_)                                            \
      _Pragma("unroll")                                                          \
      for (int kh_ = 0; kh_ < 2; ++kh_)                                          \
        dst[n2_][kh_] = *(const bf16x8*)((const char*)&lds[buf][1][half][0] +    \
            lds_half_off(wn*32 + n2_*16 + l15, kh_*32 + l4*8));                  \
  } while (0)
#define MMA(hA, hB, bsrc) do {                                                   \
    __builtin_amdgcn_s_setprio(1);                                               \
    _Pragma("unroll")                                                            \
    for (int m4_ = 0; m4_ < 4; ++m4_)                                            \
      _Pragma("unroll")                                                          \
      for (int n2_ = 0; n2_ < 2; ++n2_)                                          \
        _Pragma("unroll")                                                        \
        for (int kh_ = 0; kh_ < 2; ++kh_)                                        \
          acc[hA][m4_][hB][n2_] = __builtin_amdgcn_mfma_f32_16x16x32_bf16(       \
              afr[m4_][kh_], bsrc[n2_][kh_], acc[hA][m4_][hB][n2_], 0, 0, 0);    \
    __builtin_amdgcn_s_setprio(0);                                               \
  } while (0)
#define WAITV(n)  asm volatile("s_waitcnt vmcnt(" #n ")" ::: "memory")
#define GATE()    do { asm volatile("s_waitcnt lgkmcnt(0)" ::: "memory");        \
                       __builtin_amdgcn_sched_barrier(0); } while (0)
#define BAR()     do { IRFENCE(); __builtin_amdgcn_s_barrier(); IRFENCE(); } while (0)

  STAGEH(0, 0, 0, 0);
  STAGEH(1, 0, 0, 0);
  STAGEH(1, 1, 0, 0);
  STAGEH(0, 1, 0, 0);
  WAITV(4);
  BAR();

  for (int t = 0; t < NT; ++t) {
    const int c = t & 1;
    const bool last = (t == NT - 1);
    RDA(c, 0);
    RDB(c, 0, bfr0);
    if (!last) STAGEH(0, 0, t+1, c^1);
    if (last) WAITV(2); else WAITV(4);
    BAR(); GATE();
    MMA(0, 0, bfr0);
    RDB(c, 1, bfr1);
    if (!last) STAGEH(1, 0, t+1, c^1);
    if (last) WAITV(0); else WAITV(4);
    BAR(); GATE();
    MMA(0, 1, bfr1);
    RDA(c, 1);
    if (!last) STAGEH(1, 1, t+1, c^1);
    BAR(); GATE();
    MMA(1, 0, bfr0);
    if (!last) STAGEH(0, 1, t+1, c^1);
    WAITV(4);
    BAR(); GATE();
    MMA(1, 1, bfr1);
  }

  #pragma unroll
  for (int hA = 0; hA < 2; ++hA)
    #pragma unroll
    for (int m4 = 0; m4 < 4; ++m4) {
      const int row = tm*256 + hA*128 + wm*64 + m4*16 + l4*4;
      #pragma unroll
      for (int hB = 0; hB < 2; ++hB)
        #pragma unroll
        for (int n2 = 0; n2 < 2; ++n2) {
          const int col = tn*256 + hB*128 + wn*32 + n2*16 + l15;
          const float bv = (MODE == 3) ? 0.0f : bias[col];
          #pragma unroll
          for (int r = 0; r < 4; ++r) {
            const size_t idx = (size_t)(row + r) * N + col;
            float vv = acc[hA][m4][hB][n2][r] + bv;
            if (MODE == 0) {
              ((unsigned short*)out)[idx] = f2bf(vv);
            } else if (MODE == 1) {
              vv = 0.5f * vv * (1.0f + erff(vv * 0.70710678118654752f));
              ((unsigned short*)out)[idx] = f2bf(vv);
            } else if (MODE == 2) {
              ((float*)out)[idx] += vv;
            } else {
              ((float*)out)[idx] = vv;
            }
          }
        }
    }
#undef STAGEH
#undef RDA
#undef RDB
#undef MMA
#undef WAITV
#undef GATE
#undef BAR
}

// ---------------- flash attention v9: no LDS staging (K/V L2-resident),
// zero barriers, waves fully independent. K read direct from xqkv, V direct
// from vt (16B/lane loads, L2 hits). pl stays per-wave LDS (in-order DS).
// Softmax: no-max (scores bounded), P = 2^(st*C1).
__global__ __launch_bounds__(256, 4) void attn_fwd(
    const bf16_t* __restrict__ xqkv, const bf16_t* __restrict__ vt,
    unsigned short* __restrict__ ctx) {
  __shared__ __align__(16) bf16_t pl[4][16*64];
  const int tid = threadIdx.x, lane = tid & 63, wave = tid >> 6;
  const int orig = blockIdx.x;
  const int wg = (orig & 7) * 96 + (orig >> 3);
  const int qb16 = wg & 15;
  const int bh = wg >> 4;
  const int b = bh / TH, h = bh % TH;
  const bf16_t* qp = xqkv + (size_t)b*TS*TQKV + h*THD;
  const bf16_t* kp = xqkv + (size_t)b*TS*TQKV + TD + h*THD;
  const bf16_t* vp = vt + (size_t)bh*THD*TS;
  const int l15 = lane & 15, l4 = lane >> 4;
  const int qrow0 = qb16*128 + wave*32;
  const float C1 = 0.18033688011112042f;  // 0.125 * log2(e)
  bf16x8 qf[2][2];
  #pragma unroll
  for (int mi = 0; mi < 2; ++mi)
    #pragma unroll
    for (int kh = 0; kh < 2; ++kh)
      qf[mi][kh] = *(const bf16x8*)(qp + (size_t)(qrow0 + mi*16 + l15)*TQKV + kh*32 + l4*8);
  f32x4 o[2][4] = {};
  float rl[2] = {0.0f, 0.0f};
  const int flipw = (l15 & 7) << 3;

  for (int t = 0; t < TS/64; ++t) {
    // ---- swapped QK^T: kf direct from global (L2-resident) ----
    f32x4 st[2][4] = {};
    #pragma unroll
    for (int nj = 0; nj < 4; ++nj) {
      const bf16_t* krow = kp + (size_t)(t*64 + nj*16 + l15)*TQKV;
      bf16x8 kf0 = *(const bf16x8*)(krow + l4*8);
      bf16x8 kf1 = *(const bf16x8*)(krow + 32 + l4*8);
      st[0][nj] = __builtin_amdgcn_mfma_f32_16x16x32_bf16(kf0, qf[0][0], st[0][nj], 0, 0, 0);
      st[0][nj] = __builtin_amdgcn_mfma_f32_16x16x32_bf16(kf1, qf[0][1], st[0][nj], 0, 0, 0);
      st[1][nj] = __builtin_amdgcn_mfma_f32_16x16x32_bf16(kf0, qf[1][0], st[1][nj], 0, 0, 0);
      st[1][nj] = __builtin_amdgcn_mfma_f32_16x16x32_bf16(kf1, qf[1][1], st[1][nj], 0, 0, 0);
    }
    // ---- per-mi: P = 2^(st*C1) -> pl -> pa (in-order per-wave DS) ----
    bf16x8 pa[2][2];
    #pragma unroll
    for (int mi = 0; mi < 2; ++mi) {
      float rs = 0.0f;
      #pragma unroll
      for (int nj = 0; nj < 4; ++nj) {
        float p0 = fexp2(st[mi][nj][0]*C1);
        float p1 = fexp2(st[mi][nj][1]*C1);
        float p2 = fexp2(st[mi][nj][2]*C1);
        float p3 = fexp2(st[mi][nj][3]*C1);
        rs += (p0+p1)+(p2+p3);
        bf16x4 pk;
        pk[0] = (bf16_t)p0; pk[1] = (bf16_t)p1; pk[2] = (bf16_t)p2; pk[3] = (bf16_t)p3;
        const int colb = (nj*16 + l4*4) ^ flipw;
        *(bf16x4*)(&pl[wave][l15*64 + colb]) = pk;
      }
      rs += __shfl_xor(rs, 16);
      rs += __shfl_xor(rs, 32);
      rl[mi] += rs;
      pa[mi][0] = *(const bf16x8*)&pl[wave][l15*64 + ((l4*8) ^ flipw)];
      pa[mi][1] = *(const bf16x8*)&pl[wave][l15*64 + ((32 + l4*8) ^ flipw)];
    }
    // ---- PV: vf direct from vt (contiguous 16B along s, L2-resident) ----
    #pragma unroll
    for (int df = 0; df < 4; ++df) {
      const bf16_t* vrow = vp + (size_t)(df*16 + l15)*TS + t*64;
      bf16x8 vf0 = *(const bf16x8*)(vrow + l4*8);
      bf16x8 vf1 = *(const bf16x8*)(vrow + 32 + l4*8);
      o[0][df] = __builtin_amdgcn_mfma_f32_16x16x32_bf16(pa[0][0], vf0, o[0][df], 0, 0, 0);
      o[0][df] = __builtin_amdgcn_mfma_f32_16x16x32_bf16(pa[0][1], vf1, o[0][df], 0, 0, 0);
      o[1][df] = __builtin_amdgcn_mfma_f32_16x16x32_bf16(pa[1][0], vf0, o[1][df], 0, 0, 0);
      o[1][df] = __builtin_amdgcn_mfma_f32_16x16x32_bf16(pa[1][1], vf1, o[1][df], 0, 0, 0);
    }
  }
  #pragma unroll
  for (int mi = 0; mi < 2; ++mi) {
    const float inv = 1.0f / rl[mi];
    #pragma unroll
    for (int r = 0; r < 4; ++r) {
      const float invr = __shfl(inv, l4*4 + r, 16);
      const size_t rowoff = (size_t)b*TS*TD + (size_t)(qrow0 + mi*16 + l4*4 + r)*TD + h*THD;
      #pragma unroll
      for (int df = 0; df < 4; ++df)
        ctx[rowoff + df*16 + l15] = f2bf(o[mi][df][r] * invr);
    }
  }
}

extern "C" void kernel_launch(void* const* d_in, const int* in_sizes, int n_in,
                              void* d_out, int out_size, void* d_ws, size_t ws_size,
                              hipStream_t stream) {
  (void)in_sizes; (void)n_in; (void)out_size;
  const int*   ids  = (const int*)  d_in[0];
  const float* emb  = (const float*)d_in[1];
  const float* q_w  = (const float*)d_in[2];
  const float* q_b  = (const float*)d_in[3];
  const float* k_w  = (const float*)d_in[4];
  const float* k_b  = (const float*)d_in[5];
  const float* v_w  = (const float*)d_in[6];
  const float* v_b  = (const float*)d_in[7];
  const float* o_w  = (const float*)d_in[8];
  const float* o_b  = (const float*)d_in[9];
  const float* f1_w = (const float*)d_in[10];
  const float* f1_b = (const float*)d_in[11];
  const float* f2_w = (const float*)d_in[12];
  const float* f2_b = (const float*)d_in[13];
  const float* n1_w = (const float*)d_in[14];
  const float* n1_b = (const float*)d_in[15];
  const float* n2_w = (const float*)d_in[16];
  const float* n2_b = (const float*)d_in[17];
  const float* fn_w = (const float*)d_in[18];
  const float* fn_b = (const float*)d_in[19];

  char* ws = (char*)d_ws;
  size_t off = 0;
  auto alloc = [&](size_t bytes) -> void* {
    void* p = ws + off;
    off += (bytes + 255) & ~(size_t)255;
    return p;
  };
  float*          h    = (float*)         alloc((size_t)TT*TD*4);
  unsigned short* xn   = (unsigned short*)alloc((size_t)TT*TD*2);
  unsigned short* xqkv = (unsigned short*)alloc((size_t)TT*TQKV*2);
  unsigned short* cb   = (unsigned short*)alloc((size_t)TT*TD*2);
  unsigned short* ffb  = (unsigned short*)alloc((size_t)TT*TFF*2);
  unsigned short* cpart= (unsigned short*)alloc((size_t)4*TT*TD*2);
  unsigned short* wqkv = (unsigned short*)alloc((size_t)TL*TQKV*TD*2);
  unsigned short* wot  = (unsigned short*)alloc((size_t)TL*TD*TD*2);
  unsigned short* wf1t = (unsigned short*)alloc((size_t)TL*TD*TFF*2);
  unsigned short* wf2t = (unsigned short*)alloc((size_t)TL*TD*TFF*2);
  unsigned short* embb = (unsigned short*)alloc((size_t)TV*TD*2);
  float*          bqkv = (float*)         alloc((size_t)TL*TQKV*4);
  if (off > ws_size) return;
  bf16_t* vt = (bf16_t*)ffb;   // aliased: used before FF1 writes ffb

  transpose_to_bf16<<<dim3((TD/64)*(TD/64), TL), 256, 0, stream>>>(q_w, wqkv, TD, TD, 0,    (size_t)TQKV*TD);
  transpose_to_bf16<<<dim3((TD/64)*(TD/64), TL), 256, 0, stream>>>(k_w, wqkv, TD, TD, TD,   (size_t)TQKV*TD);
  transpose_to_bf16<<<dim3((TD/64)*(TD/64), TL), 256, 0, stream>>>(v_w, wqkv, TD, TD, 2*TD, (size_t)TQKV*TD);
  transpose_to_bf16<<<dim3((TD/64)*(TD/64), TL), 256, 0, stream>>>(o_w, wot, TD, TD, 0, (size_t)TD*TD);
  transpose_to_bf16<<<dim3((TD/64)*(TFF/64), TL), 256, 0, stream>>>(f1_w, wf1t, TD, TFF, 0, (size_t)TD*TFF);
  transpose_to_bf16<<<dim3((TFF/64)*(TD/64), TL), 256, 0, stream>>>(f2_w, wf2t, TFF, TD, 0, (size_t)TD*TFF);
  pack_qkv_bias<<<TL, TD, 0, stream>>>(q_b, k_b, v_b, bqkv);
  convert_bf16_k<<<(TV*TD)/1024, 256, 0, stream>>>(emb, embb);
  embed_rope<<<TT, 256, 0, stream>>>(ids, emb, h);

  ln_fwd<<<TT, 256, 0, stream>>>(h, n1_w, n1_b, xn);
  for (int lay = 0; lay < TL; ++lay) {
    gemm_bt<4><<<(TT/128)*(TQKV/128), 256, 0, stream>>>((const bf16_t*)xn,
        (const bf16_t*)(wqkv + (size_t)lay*TQKV*TD), bqkv + lay*TQKV, xqkv, vt, TQKV, TD, TQKV/128);
    attn_fwd<<<TB*TH*(TS/128), 256, 0, stream>>>((const bf16_t*)xqkv, vt, cb);
    // O-proj split-K x2 -> bf16 partials; reduce + bias fused into ln2
    gemm_bt<5><<<dim3((TT/128)*(TD/128), 2), 256, 0, stream>>>((const bf16_t*)cb,
        (const bf16_t*)(wot + (size_t)lay*TD*TD), nullptr, cpart, nullptr, TD, TD, TD/128);
    ln_fused<2><<<TT, 256, 0, stream>>>(h, cpart, o_b + lay*TD, n2_w + lay*TD, n2_b + lay*TD, xn);
    gemm_bt<1><<<(TT/128)*(TFF/128), 256, 0, stream>>>((const bf16_t*)xn,
        (const bf16_t*)(wf1t + (size_t)lay*TD*TFF), f1_b + lay*TFF, ffb, nullptr, TFF, TD, TFF/128);
    // FF2 split-K x4 -> bf16 partials; reduce fused into next LN
    gemm_bt<5><<<dim3((TT/128)*(TD/128), 4), 256, 0, stream>>>((const bf16_t*)ffb,
        (const bf16_t*)(wf2t + (size_t)lay*TD*TFF), nullptr, cpart, nullptr, TD, TFF, TD/128);
    if (lay < TL - 1) {
      ln_fused<4><<<TT, 256, 0, stream>>>(h, cpart, f2_b + lay*TD,
          n1_w + (lay+1)*TD, n1_b + (lay+1)*TD, xn);
    } else {
      ln_fused<4><<<TT, 256, 0, stream>>>(h, cpart, f2_b + lay*TD, fn_w, fn_b, xn);
    }
  }
  gemm256<3><<<32*(TV/256), 512, 0, stream>>>((const bf16_t*)xn,
      (const bf16_t*)embb, nullptr, d_out, TV, TD, TV/256);
}

// Round 16
// 2197.150 us; speedup vs baseline: 1.2744x; 1.2744x over previous
//
#include <hip/hip_runtime.h>
#include <hip/hip_bf16.h>
#include <cstdint>
#include <cstddef>

#define TB 4
#define TS 2048
#define TD 768
#define TH 12
#define THD 64
#define TL 6
#define TV 32000
#define TFF 3072
#define TT (TB*TS)   // 8192 tokens
#define TQKV 2304    // fused QKV width

typedef __bf16 bf16_t;
typedef __attribute__((ext_vector_type(8))) __bf16 bf16x8;
typedef __attribute__((ext_vector_type(4))) __bf16 bf16x4;
typedef __attribute__((ext_vector_type(4))) float f32x4;

__device__ __forceinline__ unsigned short f2bf(float f) {
  union { float f; unsigned u; } x; x.f = f;
  unsigned r = x.u + 0x7fffu + ((x.u >> 16) & 1u);
  return (unsigned short)(r >> 16);
}
__device__ __forceinline__ float bf2f(unsigned short u) {
  union { unsigned u; float f; } x; x.u = (unsigned)u << 16; return x.f;
}

// v_exp_f32 computes 2^x natively
__device__ __forceinline__ float fexp2(float x) {
  float r; asm("v_exp_f32 %0, %1" : "=v"(r) : "v"(x)); return r;
}

// async global->LDS, 16B per lane. lds base must be wave-uniform.
__device__ __forceinline__ void gld_lds16(const void* g, void* l) {
  unsigned loff = (unsigned)(uintptr_t)l;
  __builtin_amdgcn_global_load_lds(
      (const __attribute__((address_space(1))) unsigned int*)(uintptr_t)g,
      (__attribute__((address_space(3))) unsigned int*)(uintptr_t)loff, 16, 0, 0);
}

#define IRFENCE() asm volatile("" ::: "memory")

// ---------------- embedding gather + RoPE (fp32) ----------------
__global__ void embed_rope(const int* __restrict__ ids, const float* __restrict__ emb,
                           float* __restrict__ h) {
  int t = blockIdx.x;
  int s = t & (TS - 1);
  int id = ids[t];
  const float* row = emb + (size_t)id * TD;
  float* out = h + (size_t)t * TD;
  for (int p = threadIdx.x; p < TD/2; p += blockDim.x) {
    float xe = row[2*p], xo = row[2*p+1];
    float inv = expf(-(float)(2*p) * (9.210340371976184f / (float)TD)); // 10000^{-2p/D}
    float ang = (float)s * inv;
    float c = cosf(ang), sn = sinf(ang);
    out[2*p]   = xe*c - xo*sn;
    out[2*p+1] = xo*c + xe*sn;
  }
}

// ---------------- LayerNorm fp32 -> bf16 (float4 loads, G13) ----------------
__global__ __launch_bounds__(256) void ln_fwd(const float* __restrict__ x,
                                              const float* __restrict__ w,
                                              const float* __restrict__ b,
                                              unsigned short* __restrict__ y) {
  int row = blockIdx.x;
  const float* xr = x + (size_t)row * TD;
  int tid = threadIdx.x;
  float4 v = {0.f, 0.f, 0.f, 0.f};
  if (tid < 192) v = *(const float4*)(xr + tid*4);
  float s = (v.x+v.y)+(v.z+v.w);
  float q = (v.x*v.x+v.y*v.y)+(v.z*v.z+v.w*v.w);
  for (int o = 32; o; o >>= 1) { s += __shfl_down(s, o); q += __shfl_down(q, o); }
  __shared__ float ss[4], sq[4];
  int wave = tid >> 6, lane = tid & 63;
  if (lane == 0) { ss[wave] = s; sq[wave] = q; }
  __syncthreads();
  s = ss[0]+ss[1]+ss[2]+ss[3];
  q = sq[0]+sq[1]+sq[2]+sq[3];
  float mean = s * (1.0f/TD);
  float var  = q * (1.0f/TD) - mean*mean;
  float rstd = rsqrtf(var + 1e-5f);
  if (tid < 192) {
    const float4 wv = *(const float4*)(w + tid*4);
    const float4 bv = *(const float4*)(b + tid*4);
    ushort4 o4;
    o4.x = f2bf((v.x-mean)*rstd*wv.x + bv.x);
    o4.y = f2bf((v.y-mean)*rstd*wv.y + bv.y);
    o4.z = f2bf((v.z-mean)*rstd*wv.z + bv.z);
    o4.w = f2bf((v.w-mean)*rstd*wv.w + bv.w);
    *(ushort4*)(y + (size_t)row*TD + tid*4) = o4;
  }
}

// ---------------- fused: h += Sum(NPART bf16 partials) [+ pbias]; y = LN(h) ----------------
template<int NPART>
__global__ __launch_bounds__(256) void ln_fused(
    float* __restrict__ hbuf, const unsigned short* __restrict__ parts,
    const float* __restrict__ pbias,
    const float* __restrict__ w, const float* __restrict__ b,
    unsigned short* __restrict__ y) {
  int row = blockIdx.x;
  int tid = threadIdx.x;
  float4 v = {0.f, 0.f, 0.f, 0.f};
  if (tid < 192) {
    v = *(const float4*)(hbuf + (size_t)row*TD + tid*4);
    #pragma unroll
    for (int p = 0; p < NPART; ++p) {
      ushort4 u = *(const ushort4*)(parts + (size_t)p*TT*TD + (size_t)row*TD + tid*4);
      v.x += bf2f(u.x); v.y += bf2f(u.y); v.z += bf2f(u.z); v.w += bf2f(u.w);
    }
    if (pbias) {
      float4 pb = *(const float4*)(pbias + tid*4);
      v.x += pb.x; v.y += pb.y; v.z += pb.z; v.w += pb.w;
    }
  }
  float s = (v.x+v.y)+(v.z+v.w);
  float q = (v.x*v.x+v.y*v.y)+(v.z*v.z+v.w*v.w);
  for (int o = 32; o; o >>= 1) { s += __shfl_down(s, o); q += __shfl_down(q, o); }
  __shared__ float ss[4], sq[4];
  int wave = tid >> 6, lane = tid & 63;
  if (lane == 0) { ss[wave] = s; sq[wave] = q; }
  __syncthreads();
  s = ss[0]+ss[1]+ss[2]+ss[3];
  q = sq[0]+sq[1]+sq[2]+sq[3];
  float mean = s * (1.0f/TD);
  float var  = q * (1.0f/TD) - mean*mean;
  float rstd = rsqrtf(var + 1e-5f);
  if (tid < 192) {
    *(float4*)(hbuf + (size_t)row*TD + tid*4) = v;   // updated residual stream
    const float4 wv = *(const float4*)(w + tid*4);
    const float4 bv = *(const float4*)(b + tid*4);
    ushort4 o4;
    o4.x = f2bf((v.x-mean)*rstd*wv.x + bv.x);
    o4.y = f2bf((v.y-mean)*rstd*wv.y + bv.y);
    o4.z = f2bf((v.z-mean)*rstd*wv.z + bv.z);
    o4.w = f2bf((v.w-mean)*rstd*wv.w + bv.w);
    *(ushort4*)(y + (size_t)row*TD + tid*4) = o4;
  }
}

// ---------------- weight transpose (K x N fp32) -> (N x K bf16) ----------------
__global__ __launch_bounds__(256) void transpose_to_bf16(const float* __restrict__ W,
                                                         unsigned short* __restrict__ Wt,
                                                         int K, int N, int row_off,
                                                         size_t lstride) {
  int ntn = N / 64;
  int tk = (blockIdx.x / ntn) * 64;
  int tn = (blockIdx.x % ntn) * 64;
  const float* Wb = W + (size_t)blockIdx.y * K * N;
  unsigned short* Ob = Wt + (size_t)blockIdx.y * lstride;
  __shared__ float tile[64][65];
  int tid = threadIdx.x;
  int c = tid & 63, w = tid >> 6;
  #pragma unroll
  for (int i = 0; i < 16; ++i) {
    int r = i*4 + w;
    tile[r][c] = Wb[(size_t)(tk + r) * N + tn + c];
  }
  __syncthreads();
  #pragma unroll
  for (int i = 0; i < 16; ++i) {
    int r = i*4 + w;
    Ob[(size_t)(row_off + tn + r) * K + tk + c] = f2bf(tile[c][r]);
  }
}

// ---------------- pack q/k/v biases into one [L][2304] buffer ----------------
__global__ void pack_qkv_bias(const float* __restrict__ qb, const float* __restrict__ kb,
                              const float* __restrict__ vb, float* __restrict__ out) {
  int lay = blockIdx.x, i = threadIdx.x;
  out[lay*TQKV + i]        = qb[lay*TD + i];
  out[lay*TQKV + TD + i]   = kb[lay*TD + i];
  out[lay*TQKV + 2*TD + i] = vb[lay*TD + i];
}

// ---------------- fp32 -> bf16 convert (emb) ----------------
__global__ void convert_bf16_k(const float* __restrict__ in, unsigned short* __restrict__ out) {
  size_t i = ((size_t)blockIdx.x * 256 + threadIdx.x) * 4;
  float4 v = *(const float4*)(in + i);
  ushort4 o;
  o.x = f2bf(v.x); o.y = f2bf(v.y); o.z = f2bf(v.z); o.w = f2bf(v.w);
  *(ushort4*)(out + i) = o;
}

// ---------------- 128^2 GEMM v2: 2-phase double-buffer, counted vmcnt, T2 swizzle ----
// MODE 0: bf16 out + bias. 1: + fast GELU. 2: fp32 +=. 3: fp32 =.
// MODE 4: QKV fused — Q/K cols -> out, V cols -> out2 transposed vt[bh][d][s].
// MODE 5: split-K — gridDim.y = #slices; bf16 partial (no bias).
template<int MODE>
__global__ __launch_bounds__(256, 2) void gemm_bt(
    const bf16_t* __restrict__ A, const bf16_t* __restrict__ Bt,
    const float* __restrict__ bias, void* __restrict__ out,
    void* __restrict__ out2,
    int N, int K, int ntn) {
  __shared__ __align__(16) bf16_t As[2][128*64];
  __shared__ __align__(16) bf16_t Bs[2][128*64];
  const int tid = threadIdx.x;
  const int lane = tid & 63;
  const int wave = tid >> 6;
  const int wm = wave >> 1, wn = wave & 1;
  const int nwg = gridDim.x;
  const int orig = blockIdx.x;
  const int qd = nwg >> 3, rr = nwg & 7;
  const int xcd = orig & 7, sub = orig >> 3;
  const int wg = (xcd < rr ? xcd*(qd+1) : rr*(qd+1) + (xcd-rr)*qd) + sub;
  const int tm = wg / ntn, tn = wg % ntn;
  const int nslice = (MODE == 5) ? gridDim.y : 1;
  const int ks = (MODE == 5) ? blockIdx.y : 0;
  const int koff = ks * (K / nslice);
  const bf16_t* Ab = A + (size_t)tm * 128 * K + koff;
  const bf16_t* Bb = Bt + (size_t)tn * 128 * K + koff;
  const int lr = lane >> 3;                  // 0..7 (row within 8-row stage group)
  const int lc = ((lane & 7) ^ lr) * 8;      // pre-swizzled source col (elements)
  const int l15 = lane & 15, l4 = lane >> 4;
  const int flip = (l15 & 7) << 3;           // read-side swizzle (elements)
  const int NT = K / (64 * nslice);
  f32x4 acc[4][4] = {};

#define STAGE(t, buf) do {                                                   \
    _Pragma("unroll")                                                        \
    for (int it = 0; it < 4; ++it) {                                         \
      const int r0 = it*32 + wave*8;                                         \
      gld_lds16(Ab + (size_t)(r0 + lr)*K + (t)*64 + lc, &As[buf][r0*64 + lr*64]); \
      gld_lds16(Bb + (size_t)(r0 + lr)*K + (t)*64 + lc, &Bs[buf][r0*64 + lr*64]); \
    }                                                                        \
  } while (0)

  STAGE(0, 0);
  for (int t = 0; t < NT; ++t) {
    const int cur = t & 1;
    if (t < NT - 1) {
      STAGE(t+1, cur^1);
      asm volatile("s_waitcnt vmcnt(8)" ::: "memory");   // tile-t loads resident
    } else {
      asm volatile("s_waitcnt vmcnt(0)" ::: "memory");
    }
    IRFENCE(); __builtin_amdgcn_s_barrier(); IRFENCE();
    #pragma unroll
    for (int kh = 0; kh < 2; ++kh) {
      bf16x8 af[4], bfr[4];
      #pragma unroll
      for (int i = 0; i < 4; ++i)
        af[i] = *(const bf16x8*)&As[cur][(wm*64 + i*16 + l15)*64 + ((kh*32 + l4*8) ^ flip)];
      #pragma unroll
      for (int i = 0; i < 4; ++i)
        bfr[i] = *(const bf16x8*)&Bs[cur][(wn*64 + i*16 + l15)*64 + ((kh*32 + l4*8) ^ flip)];
      #pragma unroll
      for (int mi = 0; mi < 4; ++mi)
        #pragma unroll
        for (int ni = 0; ni < 4; ++ni)
          acc[mi][ni] = __builtin_amdgcn_mfma_f32_16x16x32_bf16(af[mi], bfr[ni], acc[mi][ni], 0, 0, 0);
    }
    IRFENCE(); __builtin_amdgcn_s_barrier(); IRFENCE();  // all reads of cur done before overwrite
  }
#undef STAGE
  const int rb = tm*128 + wm*64 + l4*4;
  const int cbase = tn*128 + wn*64 + l15;
  const bool vsec = (MODE == 4) && (tn >= (2*TD)/128);   // block-uniform
  #pragma unroll
  for (int mi = 0; mi < 4; ++mi) {
    #pragma unroll
    for (int ni = 0; ni < 4; ++ni) {
      const int c = cbase + ni*16;
      const float bv = (MODE == 3 || MODE == 5) ? 0.0f : bias[c];
      if (MODE == 4 && vsec) {
        // V section: write transposed to vt[bh][d][s], 4 rows -> 4 consecutive s
        const int cc = c - 2*TD;
        const int hh = cc >> 6, d = cc & 63;
        const int row0 = rb + mi*16;
        const int bidx = row0 >> 11, s = row0 & (TS-1);
        ushort4 o4;
        o4.x = f2bf(acc[mi][ni][0] + bv);
        o4.y = f2bf(acc[mi][ni][1] + bv);
        o4.z = f2bf(acc[mi][ni][2] + bv);
        o4.w = f2bf(acc[mi][ni][3] + bv);
        *(ushort4*)((unsigned short*)out2 + ((size_t)(bidx*TH + hh)*THD + d)*TS + s) = o4;
        continue;
      }
      #pragma unroll
      for (int r = 0; r < 4; ++r) {
        const size_t idx = (size_t)(rb + mi*16 + r) * N + c;
        float vv = acc[mi][ni][r] + bv;
        if (MODE == 0 || MODE == 4) {
          ((unsigned short*)out)[idx] = f2bf(vv);
        } else if (MODE == 1) {
          // fast GELU (tanh form): x * e/(1+e), e = 2^(x*(2.3022102+0.102944*x^2))
          float z = vv * (2.3022102f + 0.102944f * vv * vv);
          z = fminf(z, 30.0f);
          float e = fexp2(z);
          vv = vv * e / (1.0f + e);
          ((unsigned short*)out)[idx] = f2bf(vv);
        } else if (MODE == 2) {
          ((float*)out)[idx] += vv;
        } else if (MODE == 5) {
          ((unsigned short*)out)[(size_t)ks*TT*TD + idx] = f2bf(vv);
        } else {
          ((float*)out)[idx] = vv;
        }
      }
    }
  }
}

// ---------------- 256^2 deep-pipelined GEMM (logits only: grid 4000) ----------------
// P3's WAITV(4) is REQUIRED: it establishes A0,B0(t+1) residency before iteration
// t+1's P0 ds_reads (which execute BEFORE P0's own vmcnt wait in program order).
__device__ __forceinline__ int lds_half_off(int R, int C) {
  int lin = ((((R >> 4) << 1) | (C >> 5)) << 10) | ((R & 15) << 6) | ((C & 31) << 1);
  return lin ^ (((R >> 3) & 1) << 5);
}

template<int MODE>
__global__ __launch_bounds__(512, 2) void gemm256(
    const bf16_t* __restrict__ A, const bf16_t* __restrict__ Bt,
    const float* __restrict__ bias, void* __restrict__ out,
    int N, int K, int ntn) {
  __shared__ __align__(16) bf16_t lds[2][2][2][8192];  // [buf][mat][half][16KB]
  const int tid = threadIdx.x;
  const int lane = tid & 63;
  const int wave = tid >> 6;        // 0..7
  const int wm = wave >> 2;         // 0..1
  const int wn = wave & 3;          // 0..3
  const int orig = blockIdx.x;
  const int grp = orig >> 8;        // 8-tn group (ragged tail ok)
  const int rem = orig & 255;
  const int tn = grp*8 + (rem >> 5);
  const int tm = rem & 31;
  const bf16_t* Ab = A  + (size_t)tm * 256 * K;
  const bf16_t* Bb = Bt + (size_t)tn * 256 * K;
  const int l15 = lane & 15, l4 = lane >> 4;
  const int s_row = wave*16 + (lane >> 2);
  const int s_col0 = ((lane & 3) * 8) ^ ((lane >= 32) ? 16 : 0);
  const int NT = K >> 6;

  f32x4 acc[2][4][2][2] = {};
  bf16x8 afr[4][2], bfr0[2][2], bfr1[2][2];

#define STAGEH(mat, half, kt, buf) do {                                          \
    const bf16_t* base_ = (mat) ? Bb : Ab;                                       \
    _Pragma("unroll")                                                            \
    for (int j_ = 0; j_ < 2; ++j_)                                               \
      gld_lds16(base_ + (size_t)((half)*128 + s_row)*K + (kt)*64 + j_*32 + s_col0, \
                &lds[buf][mat][half][(wave*2 + j_) * 512]);                      \
  } while (0)
#define RDA(buf, half) do {                                                      \
    _Pragma("unroll")                                                            \
    for (int m4_ = 0; m4_ < 4; ++m4_)                                            \
      _Pragma("unroll")                                                          \
      for (int kh_ = 0; kh_ < 2; ++kh_)                                          \
        afr[m4_][kh_] = *(const bf16x8*)((const char*)&lds[buf][0][half][0] +    \
            lds_half_off(wm*64 + m4_*16 + l15, kh_*32 + l4*8));                  \
  } while (0)
#define RDB(buf, half, dst) do {                                                 \
    _Pragma("unroll")                                                            \
    for (int n2_ = 0; n2_ < 2; ++n2_)                                            \
      _Pragma("unroll")                                                          \
      for (int kh_ = 0; kh_ < 2; ++kh_)                                          \
        dst[n2_][kh_] = *(const bf16x8*)((const char*)&lds[buf][1][half][0] +    \
            lds_half_off(wn*32 + n2_*16 + l15, kh_*32 + l4*8));                  \
  } while (0)
#define MMA(hA, hB, bsrc) do {                                                   \
    __builtin_amdgcn_s_setprio(1);                                               \
    _Pragma("unroll")                                                            \
    for (int m4_ = 0; m4_ < 4; ++m4_)                                            \
      _Pragma("unroll")                                                          \
      for (int n2_ = 0; n2_ < 2; ++n2_)                                          \
        _Pragma("unroll")                                                        \
        for (int kh_ = 0; kh_ < 2; ++kh_)                                        \
          acc[hA][m4_][hB][n2_] = __builtin_amdgcn_mfma_f32_16x16x32_bf16(       \
              afr[m4_][kh_], bsrc[n2_][kh_], acc[hA][m4_][hB][n2_], 0, 0, 0);    \
    __builtin_amdgcn_s_setprio(0);                                               \
  } while (0)
#define WAITV(n)  asm volatile("s_waitcnt vmcnt(" #n ")" ::: "memory")
#define GATE()    do { asm volatile("s_waitcnt lgkmcnt(0)" ::: "memory");        \
                       __builtin_amdgcn_sched_barrier(0); } while (0)
#define BAR()     do { IRFENCE(); __builtin_amdgcn_s_barrier(); IRFENCE(); } while (0)

  STAGEH(0, 0, 0, 0);
  STAGEH(1, 0, 0, 0);
  STAGEH(1, 1, 0, 0);
  STAGEH(0, 1, 0, 0);
  WAITV(4);
  BAR();

  for (int t = 0; t < NT; ++t) {
    const int c = t & 1;
    const bool last = (t == NT - 1);
    RDA(c, 0);
    RDB(c, 0, bfr0);
    if (!last) STAGEH(0, 0, t+1, c^1);
    if (last) WAITV(2); else WAITV(4);
    BAR(); GATE();
    MMA(0, 0, bfr0);
    RDB(c, 1, bfr1);
    if (!last) STAGEH(1, 0, t+1, c^1);
    if (last) WAITV(0); else WAITV(4);
    BAR(); GATE();
    MMA(0, 1, bfr1);
    RDA(c, 1);
    if (!last) STAGEH(1, 1, t+1, c^1);
    BAR(); GATE();
    MMA(1, 0, bfr0);
    if (!last) STAGEH(0, 1, t+1, c^1);
    WAITV(4);
    BAR(); GATE();
    MMA(1, 1, bfr1);
  }

  #pragma unroll
  for (int hA = 0; hA < 2; ++hA)
    #pragma unroll
    for (int m4 = 0; m4 < 4; ++m4) {
      const int row = tm*256 + hA*128 + wm*64 + m4*16 + l4*4;
      #pragma unroll
      for (int hB = 0; hB < 2; ++hB)
        #pragma unroll
        for (int n2 = 0; n2 < 2; ++n2) {
          const int col = tn*256 + hB*128 + wn*32 + n2*16 + l15;
          const float bv = (MODE == 3) ? 0.0f : bias[col];
          #pragma unroll
          for (int r = 0; r < 4; ++r) {
            const size_t idx = (size_t)(row + r) * N + col;
            float vv = acc[hA][m4][hB][n2][r] + bv;
            if (MODE == 0) {
              ((unsigned short*)out)[idx] = f2bf(vv);
            } else if (MODE == 1) {
              vv = 0.5f * vv * (1.0f + erff(vv * 0.70710678118654752f));
              ((unsigned short*)out)[idx] = f2bf(vv);
            } else if (MODE == 2) {
              ((float*)out)[idx] += vv;
            } else {
              ((float*)out)[idx] = vv;
            }
          }
        }
    }
#undef STAGEH
#undef RDA
#undef RDB
#undef MMA
#undef WAITV
#undef GATE
#undef BAR
}

// ---------------- flash attention v7 (round-14 checkpoint): no-max softmax,
// P = 2^(st*C1), double-buffered LDS staging with counted vmcnt ----------------
__global__ __launch_bounds__(256, 4) void attn_fwd(
    const bf16_t* __restrict__ xqkv, const bf16_t* __restrict__ vt,
    unsigned short* __restrict__ ctx) {
  __shared__ __align__(16) bf16_t Ks[2][64*64];
  __shared__ __align__(16) bf16_t Vs[2][64*64];
  __shared__ __align__(16) bf16_t pl[4][16*64];
  const int tid = threadIdx.x, lane = tid & 63, wave = tid >> 6;
  const int orig = blockIdx.x;
  const int wg = (orig & 7) * 96 + (orig >> 3);
  const int qb16 = wg & 15;
  const int bh = wg >> 4;
  const int b = bh / TH, h = bh % TH;
  const bf16_t* qp = xqkv + (size_t)b*TS*TQKV + h*THD;
  const bf16_t* kp = xqkv + (size_t)b*TS*TQKV + TD + h*THD;
  const bf16_t* vp = vt + (size_t)bh*THD*TS;
  const int l15 = lane & 15, l4 = lane >> 4;
  const int qrow0 = qb16*128 + wave*32;
  const float C1 = 0.18033688011112042f;  // 0.125 * log2(e)
  bf16x8 qf[2][2];
  #pragma unroll
  for (int mi = 0; mi < 2; ++mi)
    #pragma unroll
    for (int kh = 0; kh < 2; ++kh)
      qf[mi][kh] = *(const bf16x8*)(qp + (size_t)(qrow0 + mi*16 + l15)*TQKV + kh*32 + l4*8);
  const int srow = lane >> 3;
  const int scol = ((lane & 7) ^ srow) * 8;
  f32x4 o[2][4] = {};
  float rl[2] = {0.0f, 0.0f};
  const int flipw = (l15 & 7) << 3;

  #define STAGE(t, buf) do {                                                     \
    _Pragma("unroll")                                                            \
    for (int i_ = 0; i_ < 2; ++i_) {                                             \
      const int r_ = i_*32 + wave*8;                                             \
      gld_lds16(kp + (size_t)((t)*64 + r_ + srow)*TQKV + scol, &Ks[buf][r_*64]); \
      gld_lds16(vp + (size_t)(r_ + srow)*TS + (t)*64 + scol,   &Vs[buf][r_*64]); \
    }                                                                            \
  } while (0)

  STAGE(0, 0);
  for (int t = 0; t < TS/64; ++t) {
    const int cur = t & 1;
    if (t < TS/64 - 1) {
      STAGE(t+1, cur^1);
      asm volatile("s_waitcnt vmcnt(4)" ::: "memory");
    } else {
      asm volatile("s_waitcnt vmcnt(0)" ::: "memory");
    }
    IRFENCE(); __builtin_amdgcn_s_barrier(); IRFENCE();
    // ---- swapped QK^T, kf streamed per nj ----
    f32x4 st[2][4] = {};
    #pragma unroll
    for (int nj = 0; nj < 4; ++nj) {
      const int row = nj*16 + l15;
      const int flip = (row & 7) << 3;
      bf16x8 kf0 = *(const bf16x8*)&Ks[cur][row*64 + ((l4*8) ^ flip)];
      bf16x8 kf1 = *(const bf16x8*)&Ks[cur][row*64 + ((32 + l4*8) ^ flip)];
      st[0][nj] = __builtin_amdgcn_mfma_f32_16x16x32_bf16(kf0, qf[0][0], st[0][nj], 0, 0, 0);
      st[0][nj] = __builtin_amdgcn_mfma_f32_16x16x32_bf16(kf1, qf[0][1], st[0][nj], 0, 0, 0);
      st[1][nj] = __builtin_amdgcn_mfma_f32_16x16x32_bf16(kf0, qf[1][0], st[1][nj], 0, 0, 0);
      st[1][nj] = __builtin_amdgcn_mfma_f32_16x16x32_bf16(kf1, qf[1][1], st[1][nj], 0, 0, 0);
    }
    // ---- per-mi: P = 2^(st*C1) -> pl16 -> pa (in-order DS makes this safe) ----
    bf16x8 pa[2][2];
    #pragma unroll
    for (int mi = 0; mi < 2; ++mi) {
      float rs = 0.0f;
      #pragma unroll
      for (int nj = 0; nj < 4; ++nj) {
        float p0 = fexp2(st[mi][nj][0]*C1);
        float p1 = fexp2(st[mi][nj][1]*C1);
        float p2 = fexp2(st[mi][nj][2]*C1);
        float p3 = fexp2(st[mi][nj][3]*C1);
        rs += (p0+p1)+(p2+p3);
        bf16x4 pk;
        pk[0] = (bf16_t)p0; pk[1] = (bf16_t)p1; pk[2] = (bf16_t)p2; pk[3] = (bf16_t)p3;
        const int colb = (nj*16 + l4*4) ^ flipw;
        *(bf16x4*)(&pl[wave][l15*64 + colb]) = pk;
      }
      rs += __shfl_xor(rs, 16);
      rs += __shfl_xor(rs, 32);
      rl[mi] += rs;
      pa[mi][0] = *(const bf16x8*)&pl[wave][l15*64 + ((l4*8) ^ flipw)];
      pa[mi][1] = *(const bf16x8*)&pl[wave][l15*64 + ((32 + l4*8) ^ flipw)];
    }
    // ---- PV: O += P[32x64] @ V^T, vf streamed per df ----
    #pragma unroll
    for (int df = 0; df < 4; ++df) {
      const int vrow = df*16 + l15;
      const int flip = (vrow & 7) << 3;
      bf16x8 vf0 = *(const bf16x8*)&Vs[cur][vrow*64 + ((l4*8) ^ flip)];
      bf16x8 vf1 = *(const bf16x8*)&Vs[cur][vrow*64 + ((32 + l4*8) ^ flip)];
      o[0][df] = __builtin_amdgcn_mfma_f32_16x16x32_bf16(pa[0][0], vf0, o[0][df], 0, 0, 0);
      o[0][df] = __builtin_amdgcn_mfma_f32_16x16x32_bf16(pa[0][1], vf1, o[0][df], 0, 0, 0);
      o[1][df] = __builtin_amdgcn_mfma_f32_16x16x32_bf16(pa[1][0], vf0, o[1][df], 0, 0, 0);
      o[1][df] = __builtin_amdgcn_mfma_f32_16x16x32_bf16(pa[1][1], vf1, o[1][df], 0, 0, 0);
    }
    IRFENCE(); __builtin_amdgcn_s_barrier(); IRFENCE();  // protect cur before overwrite
  }
  #undef STAGE
  #pragma unroll
  for (int mi = 0; mi < 2; ++mi) {
    const float inv = 1.0f / rl[mi];
    #pragma unroll
    for (int r = 0; r < 4; ++r) {
      const float invr = __shfl(inv, l4*4 + r, 16);
      const size_t rowoff = (size_t)b*TS*TD + (size_t)(qrow0 + mi*16 + l4*4 + r)*TD + h*THD;
      #pragma unroll
      for (int df = 0; df < 4; ++df)
        ctx[rowoff + df*16 + l15] = f2bf(o[mi][df][r] * invr);
    }
  }
}

extern "C" void kernel_launch(void* const* d_in, const int* in_sizes, int n_in,
                              void* d_out, int out_size, void* d_ws, size_t ws_size,
                              hipStream_t stream) {
  (void)in_sizes; (void)n_in; (void)out_size;
  const int*   ids  = (const int*)  d_in[0];
  const float* emb  = (const float*)d_in[1];
  const float* q_w  = (const float*)d_in[2];
  const float* q_b  = (const float*)d_in[3];
  const float* k_w  = (const float*)d_in[4];
  const float* k_b  = (const float*)d_in[5];
  const float* v_w  = (const float*)d_in[6];
  const float* v_b  = (const float*)d_in[7];
  const float* o_w  = (const float*)d_in[8];
  const float* o_b  = (const float*)d_in[9];
  const float* f1_w = (const float*)d_in[10];
  const float* f1_b = (const float*)d_in[11];
  const float* f2_w = (const float*)d_in[12];
  const float* f2_b = (const float*)d_in[13];
  const float* n1_w = (const float*)d_in[14];
  const float* n1_b = (const float*)d_in[15];
  const float* n2_w = (const float*)d_in[16];
  const float* n2_b = (const float*)d_in[17];
  const float* fn_w = (const float*)d_in[18];
  const float* fn_b = (const float*)d_in[19];

  char* ws = (char*)d_ws;
  size_t off = 0;
  auto alloc = [&](size_t bytes) -> void* {
    void* p = ws + off;
    off += (bytes + 255) & ~(size_t)255;
    return p;
  };
  float*          h    = (float*)         alloc((size_t)TT*TD*4);
  unsigned short* xn   = (unsigned short*)alloc((size_t)TT*TD*2);
  unsigned short* xqkv = (unsigned short*)alloc((size_t)TT*TQKV*2);
  unsigned short* cb   = (unsigned short*)alloc((size_t)TT*TD*2);
  unsigned short* ffb  = (unsigned short*)alloc((size_t)TT*TFF*2);
  unsigned short* cpart= (unsigned short*)alloc((size_t)4*TT*TD*2);
  unsigned short* wqkv = (unsigned short*)alloc((size_t)TL*TQKV*TD*2);
  unsigned short* wot  = (unsigned short*)alloc((size_t)TL*TD*TD*2);
  unsigned short* wf1t = (unsigned short*)alloc((size_t)TL*TD*TFF*2);
  unsigned short* wf2t = (unsigned short*)alloc((size_t)TL*TD*TFF*2);
  unsigned short* embb = (unsigned short*)alloc((size_t)TV*TD*2);
  float*          bqkv = (float*)         alloc((size_t)TL*TQKV*4);
  if (off > ws_size) return;
  bf16_t* vt = (bf16_t*)ffb;   // aliased: used before FF1 writes ffb

  transpose_to_bf16<<<dim3((TD/64)*(TD/64), TL), 256, 0, stream>>>(q_w, wqkv, TD, TD, 0,    (size_t)TQKV*TD);
  transpose_to_bf16<<<dim3((TD/64)*(TD/64), TL), 256, 0, stream>>>(k_w, wqkv, TD, TD, TD,   (size_t)TQKV*TD);
  transpose_to_bf16<<<dim3((TD/64)*(TD/64), TL), 256, 0, stream>>>(v_w, wqkv, TD, TD, 2*TD, (size_t)TQKV*TD);
  transpose_to_bf16<<<dim3((TD/64)*(TD/64), TL), 256, 0, stream>>>(o_w, wot, TD, TD, 0, (size_t)TD*TD);
  transpose_to_bf16<<<dim3((TD/64)*(TFF/64), TL), 256, 0, stream>>>(f1_w, wf1t, TD, TFF, 0, (size_t)TD*TFF);
  transpose_to_bf16<<<dim3((TFF/64)*(TD/64), TL), 256, 0, stream>>>(f2_w, wf2t, TFF, TD, 0, (size_t)TD*TFF);
  pack_qkv_bias<<<TL, TD, 0, stream>>>(q_b, k_b, v_b, bqkv);
  convert_bf16_k<<<(TV*TD)/1024, 256, 0, stream>>>(emb, embb);
  embed_rope<<<TT, 256, 0, stream>>>(ids, emb, h);

  ln_fwd<<<TT, 256, 0, stream>>>(h, n1_w, n1_b, xn);
  for (int lay = 0; lay < TL; ++lay) {
    gemm_bt<4><<<(TT/128)*(TQKV/128), 256, 0, stream>>>((const bf16_t*)xn,
        (const bf16_t*)(wqkv + (size_t)lay*TQKV*TD), bqkv + lay*TQKV, xqkv, vt, TQKV, TD, TQKV/128);
    attn_fwd<<<TB*TH*(TS/128), 256, 0, stream>>>((const bf16_t*)xqkv, vt, cb);
    // O-proj split-K x2 -> bf16 partials; reduce + bias fused into ln2
    gemm_bt<5><<<dim3((TT/128)*(TD/128), 2), 256, 0, stream>>>((const bf16_t*)cb,
        (const bf16_t*)(wot + (size_t)lay*TD*TD), nullptr, cpart, nullptr, TD, TD, TD/128);
    ln_fused<2><<<TT, 256, 0, stream>>>(h, cpart, o_b + lay*TD, n2_w + lay*TD, n2_b + lay*TD, xn);
    gemm_bt<1><<<(TT/128)*(TFF/128), 256, 0, stream>>>((const bf16_t*)xn,
        (const bf16_t*)(wf1t + (size_t)lay*TD*TFF), f1_b + lay*TFF, ffb, nullptr, TFF, TD, TFF/128);
    // FF2 split-K x4 -> bf16 partials; reduce fused into next LN
    gemm_bt<5><<<dim3((TT/128)*(TD/128), 4), 256, 0, stream>>>((const bf16_t*)ffb,
        (const bf16_t*)(wf2t + (size_t)lay*TD*TFF), nullptr, cpart, nullptr, TD, TFF, TD/128);
    if (lay < TL - 1) {
      ln_fused<4><<<TT, 256, 0, stream>>>(h, cpart, f2_b + lay*TD,
          n1_w + (lay+1)*TD, n1_b + (lay+1)*TD, xn);
    } else {
      ln_fused<4><<<TT, 256, 0, stream>>>(h, cpart, f2_b + lay*TD, fn_w, fn_b, xn);
    }
  }
  gemm256<3><<<32*(TV/256), 512, 0, stream>>>((const bf16_t*)xn,
      (const bf16_t*)embb, nullptr, d_out, TV, TD, TV/256);
}

// Round 17
// 2177.682 us; speedup vs baseline: 1.2858x; 1.0089x over previous
//
#include <hip/hip_runtime.h>
#include <hip/hip_bf16.h>
#include <cstdint>
#include <cstddef>

#define TB 4
#define TS 2048
#define TD 768
#define TH 12
#define THD 64
#define TL 6
#define TV 32000
#define TFF 3072
#define TT (TB*TS)   // 8192 tokens
#define TQKV 2304    // fused QKV width

typedef __bf16 bf16_t;
typedef __attribute__((ext_vector_type(8))) __bf16 bf16x8;
typedef __attribute__((ext_vector_type(4))) __bf16 bf16x4;
typedef __attribute__((ext_vector_type(4))) float f32x4;

__device__ __forceinline__ unsigned short f2bf(float f) {
  union { float f; unsigned u; } x; x.f = f;
  unsigned r = x.u + 0x7fffu + ((x.u >> 16) & 1u);
  return (unsigned short)(r >> 16);
}
__device__ __forceinline__ float bf2f(unsigned short u) {
  union { unsigned u; float f; } x; x.u = (unsigned)u << 16; return x.f;
}

// v_exp_f32 computes 2^x natively
__device__ __forceinline__ float fexp2(float x) {
  float r; asm("v_exp_f32 %0, %1" : "=v"(r) : "v"(x)); return r;
}

// async global->LDS, 16B per lane. lds base must be wave-uniform.
__device__ __forceinline__ void gld_lds16(const void* g, void* l) {
  unsigned loff = (unsigned)(uintptr_t)l;
  __builtin_amdgcn_global_load_lds(
      (const __attribute__((address_space(1))) unsigned int*)(uintptr_t)g,
      (__attribute__((address_space(3))) unsigned int*)(uintptr_t)loff, 16, 0, 0);
}

#define IRFENCE() asm volatile("" ::: "memory")

// ---------------- embedding gather + RoPE (fp32) ----------------
__global__ void embed_rope(const int* __restrict__ ids, const float* __restrict__ emb,
                           float* __restrict__ h) {
  int t = blockIdx.x;
  int s = t & (TS - 1);
  int id = ids[t];
  const float* row = emb + (size_t)id * TD;
  float* out = h + (size_t)t * TD;
  for (int p = threadIdx.x; p < TD/2; p += blockDim.x) {
    float xe = row[2*p], xo = row[2*p+1];
    float inv = expf(-(float)(2*p) * (9.210340371976184f / (float)TD)); // 10000^{-2p/D}
    float ang = (float)s * inv;
    float c = cosf(ang), sn = sinf(ang);
    out[2*p]   = xe*c - xo*sn;
    out[2*p+1] = xo*c + xe*sn;
  }
}

// ---------------- LayerNorm fp32 -> bf16 (float4 loads, G13) ----------------
__global__ __launch_bounds__(256) void ln_fwd(const float* __restrict__ x,
                                              const float* __restrict__ w,
                                              const float* __restrict__ b,
                                              unsigned short* __restrict__ y) {
  int row = blockIdx.x;
  const float* xr = x + (size_t)row * TD;
  int tid = threadIdx.x;
  float4 v = {0.f, 0.f, 0.f, 0.f};
  if (tid < 192) v = *(const float4*)(xr + tid*4);
  float s = (v.x+v.y)+(v.z+v.w);
  float q = (v.x*v.x+v.y*v.y)+(v.z*v.z+v.w*v.w);
  for (int o = 32; o; o >>= 1) { s += __shfl_down(s, o); q += __shfl_down(q, o); }
  __shared__ float ss[4], sq[4];
  int wave = tid >> 6, lane = tid & 63;
  if (lane == 0) { ss[wave] = s; sq[wave] = q; }
  __syncthreads();
  s = ss[0]+ss[1]+ss[2]+ss[3];
  q = sq[0]+sq[1]+sq[2]+sq[3];
  float mean = s * (1.0f/TD);
  float var  = q * (1.0f/TD) - mean*mean;
  float rstd = rsqrtf(var + 1e-5f);
  if (tid < 192) {
    const float4 wv = *(const float4*)(w + tid*4);
    const float4 bv = *(const float4*)(b + tid*4);
    ushort4 o4;
    o4.x = f2bf((v.x-mean)*rstd*wv.x + bv.x);
    o4.y = f2bf((v.y-mean)*rstd*wv.y + bv.y);
    o4.z = f2bf((v.z-mean)*rstd*wv.z + bv.z);
    o4.w = f2bf((v.w-mean)*rstd*wv.w + bv.w);
    *(ushort4*)(y + (size_t)row*TD + tid*4) = o4;
  }
}

// ---------------- fused: h += Sum(NPART bf16 partials) [+ pbias]; y = LN(h) ----------------
template<int NPART>
__global__ __launch_bounds__(256) void ln_fused(
    float* __restrict__ hbuf, const unsigned short* __restrict__ parts,
    const float* __restrict__ pbias,
    const float* __restrict__ w, const float* __restrict__ b,
    unsigned short* __restrict__ y) {
  int row = blockIdx.x;
  int tid = threadIdx.x;
  float4 v = {0.f, 0.f, 0.f, 0.f};
  if (tid < 192) {
    v = *(const float4*)(hbuf + (size_t)row*TD + tid*4);
    #pragma unroll
    for (int p = 0; p < NPART; ++p) {
      ushort4 u = *(const ushort4*)(parts + (size_t)p*TT*TD + (size_t)row*TD + tid*4);
      v.x += bf2f(u.x); v.y += bf2f(u.y); v.z += bf2f(u.z); v.w += bf2f(u.w);
    }
    if (pbias) {
      float4 pb = *(const float4*)(pbias + tid*4);
      v.x += pb.x; v.y += pb.y; v.z += pb.z; v.w += pb.w;
    }
  }
  float s = (v.x+v.y)+(v.z+v.w);
  float q = (v.x*v.x+v.y*v.y)+(v.z*v.z+v.w*v.w);
  for (int o = 32; o; o >>= 1) { s += __shfl_down(s, o); q += __shfl_down(q, o); }
  __shared__ float ss[4], sq[4];
  int wave = tid >> 6, lane = tid & 63;
  if (lane == 0) { ss[wave] = s; sq[wave] = q; }
  __syncthreads();
  s = ss[0]+ss[1]+ss[2]+ss[3];
  q = sq[0]+sq[1]+sq[2]+sq[3];
  float mean = s * (1.0f/TD);
  float var  = q * (1.0f/TD) - mean*mean;
  float rstd = rsqrtf(var + 1e-5f);
  if (tid < 192) {
    *(float4*)(hbuf + (size_t)row*TD + tid*4) = v;   // updated residual stream
    const float4 wv = *(const float4*)(w + tid*4);
    const float4 bv = *(const float4*)(b + tid*4);
    ushort4 o4;
    o4.x = f2bf((v.x-mean)*rstd*wv.x + bv.x);
    o4.y = f2bf((v.y-mean)*rstd*wv.y + bv.y);
    o4.z = f2bf((v.z-mean)*rstd*wv.z + bv.z);
    o4.w = f2bf((v.w-mean)*rstd*wv.w + bv.w);
    *(ushort4*)(y + (size_t)row*TD + tid*4) = o4;
  }
}

// ---------------- weight transpose (K x N fp32) -> (N x K bf16) ----------------
__global__ __launch_bounds__(256) void transpose_to_bf16(const float* __restrict__ W,
                                                         unsigned short* __restrict__ Wt,
                                                         int K, int N, int row_off,
                                                         size_t lstride) {
  int ntn = N / 64;
  int tk = (blockIdx.x / ntn) * 64;
  int tn = (blockIdx.x % ntn) * 64;
  const float* Wb = W + (size_t)blockIdx.y * K * N;
  unsigned short* Ob = Wt + (size_t)blockIdx.y * lstride;
  __shared__ float tile[64][65];
  int tid = threadIdx.x;
  int c = tid & 63, w = tid >> 6;
  #pragma unroll
  for (int i = 0; i < 16; ++i) {
    int r = i*4 + w;
    tile[r][c] = Wb[(size_t)(tk + r) * N + tn + c];
  }
  __syncthreads();
  #pragma unroll
  for (int i = 0; i < 16; ++i) {
    int r = i*4 + w;
    Ob[(size_t)(row_off + tn + r) * K + tk + c] = f2bf(tile[c][r]);
  }
}

// ---------------- pack q/k/v biases into one [L][2304] buffer ----------------
__global__ void pack_qkv_bias(const float* __restrict__ qb, const float* __restrict__ kb,
                              const float* __restrict__ vb, float* __restrict__ out) {
  int lay = blockIdx.x, i = threadIdx.x;
  out[lay*TQKV + i]        = qb[lay*TD + i];
  out[lay*TQKV + TD + i]   = kb[lay*TD + i];
  out[lay*TQKV + 2*TD + i] = vb[lay*TD + i];
}

// ---------------- fp32 -> bf16 convert (emb) ----------------
__global__ void convert_bf16_k(const float* __restrict__ in, unsigned short* __restrict__ out) {
  size_t i = ((size_t)blockIdx.x * 256 + threadIdx.x) * 4;
  float4 v = *(const float4*)(in + i);
  ushort4 o;
  o.x = f2bf(v.x); o.y = f2bf(v.y); o.z = f2bf(v.z); o.w = f2bf(v.w);
  *(ushort4*)(out + i) = o;
}

// ---------------- 128^2 GEMM v2: 2-phase double-buffer, counted vmcnt, T2 swizzle ----
// MODE 0: bf16 out + bias. 1: + fast GELU. 2: fp32 +=. 3: fp32 =.
// MODE 4: QKV fused — Q/K cols -> out, V cols -> out2 transposed vt[bh][d][s].
// MODE 5: split-K — gridDim.y = #slices; bf16 partial (no bias).
// Epilogue bf16 stores use native casts (RNE, pk-fusable by compiler).
template<int MODE>
__global__ __launch_bounds__(256, 2) void gemm_bt(
    const bf16_t* __restrict__ A, const bf16_t* __restrict__ Bt,
    const float* __restrict__ bias, void* __restrict__ out,
    void* __restrict__ out2,
    int N, int K, int ntn) {
  __shared__ __align__(16) bf16_t As[2][128*64];
  __shared__ __align__(16) bf16_t Bs[2][128*64];
  const int tid = threadIdx.x;
  const int lane = tid & 63;
  const int wave = tid >> 6;
  const int wm = wave >> 1, wn = wave & 1;
  const int nwg = gridDim.x;
  const int orig = blockIdx.x;
  const int qd = nwg >> 3, rr = nwg & 7;
  const int xcd = orig & 7, sub = orig >> 3;
  const int wg = (xcd < rr ? xcd*(qd+1) : rr*(qd+1) + (xcd-rr)*qd) + sub;
  const int tm = wg / ntn, tn = wg % ntn;
  const int nslice = (MODE == 5) ? gridDim.y : 1;
  const int ks = (MODE == 5) ? blockIdx.y : 0;
  const int koff = ks * (K / nslice);
  const bf16_t* Ab = A + (size_t)tm * 128 * K + koff;
  const bf16_t* Bb = Bt + (size_t)tn * 128 * K + koff;
  const int lr = lane >> 3;                  // 0..7 (row within 8-row stage group)
  const int lc = ((lane & 7) ^ lr) * 8;      // pre-swizzled source col (elements)
  const int l15 = lane & 15, l4 = lane >> 4;
  const int flip = (l15 & 7) << 3;           // read-side swizzle (elements)
  const int NT = K / (64 * nslice);
  f32x4 acc[4][4] = {};

#define STAGE(t, buf) do {                                                   \
    _Pragma("unroll")                                                        \
    for (int it = 0; it < 4; ++it) {                                         \
      const int r0 = it*32 + wave*8;                                         \
      gld_lds16(Ab + (size_t)(r0 + lr)*K + (t)*64 + lc, &As[buf][r0*64 + lr*64]); \
      gld_lds16(Bb + (size_t)(r0 + lr)*K + (t)*64 + lc, &Bs[buf][r0*64 + lr*64]); \
    }                                                                        \
  } while (0)

  STAGE(0, 0);
  for (int t = 0; t < NT; ++t) {
    const int cur = t & 1;
    if (t < NT - 1) {
      STAGE(t+1, cur^1);
      asm volatile("s_waitcnt vmcnt(8)" ::: "memory");   // tile-t loads resident
    } else {
      asm volatile("s_waitcnt vmcnt(0)" ::: "memory");
    }
    IRFENCE(); __builtin_amdgcn_s_barrier(); IRFENCE();
    #pragma unroll
    for (int kh = 0; kh < 2; ++kh) {
      bf16x8 af[4], bfr[4];
      #pragma unroll
      for (int i = 0; i < 4; ++i)
        af[i] = *(const bf16x8*)&As[cur][(wm*64 + i*16 + l15)*64 + ((kh*32 + l4*8) ^ flip)];
      #pragma unroll
      for (int i = 0; i < 4; ++i)
        bfr[i] = *(const bf16x8*)&Bs[cur][(wn*64 + i*16 + l15)*64 + ((kh*32 + l4*8) ^ flip)];
      __builtin_amdgcn_s_setprio(1);
      #pragma unroll
      for (int mi = 0; mi < 4; ++mi)
        #pragma unroll
        for (int ni = 0; ni < 4; ++ni)
          acc[mi][ni] = __builtin_amdgcn_mfma_f32_16x16x32_bf16(af[mi], bfr[ni], acc[mi][ni], 0, 0, 0);
      __builtin_amdgcn_s_setprio(0);
    }
    IRFENCE(); __builtin_amdgcn_s_barrier(); IRFENCE();  // all reads of cur done before overwrite
  }
#undef STAGE
  const int rb = tm*128 + wm*64 + l4*4;
  const int cbase = tn*128 + wn*64 + l15;
  const bool vsec = (MODE == 4) && (tn >= (2*TD)/128);   // block-uniform
  #pragma unroll
  for (int mi = 0; mi < 4; ++mi) {
    #pragma unroll
    for (int ni = 0; ni < 4; ++ni) {
      const int c = cbase + ni*16;
      const float bv = (MODE == 3 || MODE == 5) ? 0.0f : bias[c];
      if (MODE == 4 && vsec) {
        // V section: write transposed to vt[bh][d][s], 4 rows -> 4 consecutive s
        const int cc = c - 2*TD;
        const int hh = cc >> 6, d = cc & 63;
        const int row0 = rb + mi*16;
        const int bidx = row0 >> 11, s = row0 & (TS-1);
        bf16x4 pk;
        pk[0] = (bf16_t)(acc[mi][ni][0] + bv);
        pk[1] = (bf16_t)(acc[mi][ni][1] + bv);
        pk[2] = (bf16_t)(acc[mi][ni][2] + bv);
        pk[3] = (bf16_t)(acc[mi][ni][3] + bv);
        *(bf16x4*)((bf16_t*)out2 + ((size_t)(bidx*TH + hh)*THD + d)*TS + s) = pk;
        continue;
      }
      #pragma unroll
      for (int r = 0; r < 4; ++r) {
        const size_t idx = (size_t)(rb + mi*16 + r) * N + c;
        float vv = acc[mi][ni][r] + bv;
        if (MODE == 0 || MODE == 4) {
          ((bf16_t*)out)[idx] = (bf16_t)vv;
        } else if (MODE == 1) {
          // fast GELU (tanh form): x * e/(1+e), e = 2^(x*(2.3022102+0.102944*x^2))
          float z = vv * (2.3022102f + 0.102944f * vv * vv);
          z = fminf(z, 30.0f);
          float e = fexp2(z);
          vv = vv * e / (1.0f + e);
          ((bf16_t*)out)[idx] = (bf16_t)vv;
        } else if (MODE == 2) {
          ((float*)out)[idx] += vv;
        } else if (MODE == 5) {
          ((bf16_t*)out)[(size_t)ks*TT*TD + idx] = (bf16_t)vv;
        } else {
          ((float*)out)[idx] = vv;
        }
      }
    }
  }
}

// ---------------- 256^2 deep-pipelined GEMM (logits only: grid 4000) ----------------
// P3's WAITV(4) is REQUIRED: it establishes A0,B0(t+1) residency before iteration
// t+1's P0 ds_reads (which execute BEFORE P0's own vmcnt wait in program order).
__device__ __forceinline__ int lds_half_off(int R, int C) {
  int lin = ((((R >> 4) << 1) | (C >> 5)) << 10) | ((R & 15) << 6) | ((C & 31) << 1);
  return lin ^ (((R >> 3) & 1) << 5);
}

template<int MODE>
__global__ __launch_bounds__(512, 2) void gemm256(
    const bf16_t* __restrict__ A, const bf16_t* __restrict__ Bt,
    const float* __restrict__ bias, void* __restrict__ out,
    int N, int K, int ntn) {
  __shared__ __align__(16) bf16_t lds[2][2][2][8192];  // [buf][mat][half][16KB]
  const int tid = threadIdx.x;
  const int lane = tid & 63;
  const int wave = tid >> 6;        // 0..7
  const int wm = wave >> 2;         // 0..1
  const int wn = wave & 3;          // 0..3
  const int orig = blockIdx.x;
  const int grp = orig >> 8;        // 8-tn group (ragged tail ok)
  const int rem = orig & 255;
  const int tn = grp*8 + (rem >> 5);
  const int tm = rem & 31;
  const bf16_t* Ab = A  + (size_t)tm * 256 * K;
  const bf16_t* Bb = Bt + (size_t)tn * 256 * K;
  const int l15 = lane & 15, l4 = lane >> 4;
  const int s_row = wave*16 + (lane >> 2);
  const int s_col0 = ((lane & 3) * 8) ^ ((lane >= 32) ? 16 : 0);
  const int NT = K >> 6;

  f32x4 acc[2][4][2][2] = {};
  bf16x8 afr[4][2], bfr0[2][2], bfr1[2][2];

#define STAGEH(mat, half, kt, buf) do {                                          \
    const bf16_t* base_ = (mat) ? Bb : Ab;                                       \
    _Pragma("unroll")                                                            \
    for (int j_ = 0; j_ < 2; ++j_)                                               \
      gld_lds16(base_ + (size_t)((half)*128 + s_row)*K + (kt)*64 + j_*32 + s_col0, \
                &lds[buf][mat][half][(wave*2 + j_) * 512]);                      \
  } while (0)
#define RDA(buf, half) do {                                                      \
    _Pragma("unroll")                                                            \
    for (int m4_ = 0; m4_ < 4; ++m4_)                                            \
      _Pragma("unroll")                                                          \
      for (int kh_ = 0; kh_ < 2; ++kh_)                                          \
        afr[m4_][kh_] = *(const bf16x8*)((const char*)&lds[buf][0][half][0] +    \
            lds_half_off(wm*64 + m4_*16 + l15, kh_*32 + l4*8));                  \
  } while (0)
#define RDB(buf, half, dst) do {                                                 \
    _Pragma("unroll")                                                            \
    for (int n2_ = 0; n2_ < 2; ++n2_)                                            \
      _Pragma("unroll")                                                          \
      for (int kh_ = 0; kh_ < 2; ++kh_)                                          \
        dst[n2_][kh_] = *(const bf16x8*)((const char*)&lds[buf][1][half][0] +    \
            lds_half_off(wn*32 + n2_*16 + l15, kh_*32 + l4*8));                  \
  } while (0)
#define MMA(hA, hB, bsrc) do {                                                   \
    __builtin_amdgcn_s_setprio(1);                                               \
    _Pragma("unroll")                                                            \
    for (int m4_ = 0; m4_ < 4; ++m4_)                                            \
      _Pragma("unroll")                                                          \
      for (int n2_ = 0; n2_ < 2; ++n2_)                                          \
        _Pragma("unroll")                                                        \
        for (int kh_ = 0; kh_ < 2; ++kh_)                                        \
          acc[hA][m4_][hB][n2_] = __builtin_amdgcn_mfma_f32_16x16x32_bf16(       \
              afr[m4_][kh_], bsrc[n2_][kh_], acc[hA][m4_][hB][n2_], 0, 0, 0);    \
    __builtin_amdgcn_s_setprio(0);                                               \
  } while (0)
#define WAITV(n)  asm volatile("s_waitcnt vmcnt(" #n ")" ::: "memory")
#define GATE()    do { asm volatile("s_waitcnt lgkmcnt(0)" ::: "memory");        \
                       __builtin_amdgcn_sched_barrier(0); } while (0)
#define BAR()     do { IRFENCE(); __builtin_amdgcn_s_barrier(); IRFENCE(); } while (0)

  STAGEH(0, 0, 0, 0);
  STAGEH(1, 0, 0, 0);
  STAGEH(1, 1, 0, 0);
  STAGEH(0, 1, 0, 0);
  WAITV(4);
  BAR();

  for (int t = 0; t < NT; ++t) {
    const int c = t & 1;
    const bool last = (t == NT - 1);
    RDA(c, 0);
    RDB(c, 0, bfr0);
    if (!last) STAGEH(0, 0, t+1, c^1);
    if (last) WAITV(2); else WAITV(4);
    BAR(); GATE();
    MMA(0, 0, bfr0);
    RDB(c, 1, bfr1);
    if (!last) STAGEH(1, 0, t+1, c^1);
    if (last) WAITV(0); else WAITV(4);
    BAR(); GATE();
    MMA(0, 1, bfr1);
    RDA(c, 1);
    if (!last) STAGEH(1, 1, t+1, c^1);
    BAR(); GATE();
    MMA(1, 0, bfr0);
    if (!last) STAGEH(0, 1, t+1, c^1);
    WAITV(4);
    BAR(); GATE();
    MMA(1, 1, bfr1);
  }

  #pragma unroll
  for (int hA = 0; hA < 2; ++hA)
    #pragma unroll
    for (int m4 = 0; m4 < 4; ++m4) {
      const int row = tm*256 + hA*128 + wm*64 + m4*16 + l4*4;
      #pragma unroll
      for (int hB = 0; hB < 2; ++hB)
        #pragma unroll
        for (int n2 = 0; n2 < 2; ++n2) {
          const int col = tn*256 + hB*128 + wn*32 + n2*16 + l15;
          const float bv = (MODE == 3) ? 0.0f : bias[col];
          #pragma unroll
          for (int r = 0; r < 4; ++r) {
            const size_t idx = (size_t)(row + r) * N + col;
            float vv = acc[hA][m4][hB][n2][r] + bv;
            if (MODE == 0) {
              ((unsigned short*)out)[idx] = f2bf(vv);
            } else if (MODE == 1) {
              vv = 0.5f * vv * (1.0f + erff(vv * 0.70710678118654752f));
              ((unsigned short*)out)[idx] = f2bf(vv);
            } else if (MODE == 2) {
              ((float*)out)[idx] += vv;
            } else {
              ((float*)out)[idx] = vv;
            }
          }
        }
    }
#undef STAGEH
#undef RDA
#undef RDB
#undef MMA
#undef WAITV
#undef GATE
#undef BAR
}

// ---------------- flash attention v7.1: round-16 structure + T5 setprio ----------------
__global__ __launch_bounds__(256, 4) void attn_fwd(
    const bf16_t* __restrict__ xqkv, const bf16_t* __restrict__ vt,
    unsigned short* __restrict__ ctx) {
  __shared__ __align__(16) bf16_t Ks[2][64*64];
  __shared__ __align__(16) bf16_t Vs[2][64*64];
  __shared__ __align__(16) bf16_t pl[4][16*64];
  const int tid = threadIdx.x, lane = tid & 63, wave = tid >> 6;
  const int orig = blockIdx.x;
  const int wg = (orig & 7) * 96 + (orig >> 3);
  const int qb16 = wg & 15;
  const int bh = wg >> 4;
  const int b = bh / TH, h = bh % TH;
  const bf16_t* qp = xqkv + (size_t)b*TS*TQKV + h*THD;
  const bf16_t* kp = xqkv + (size_t)b*TS*TQKV + TD + h*THD;
  const bf16_t* vp = vt + (size_t)bh*THD*TS;
  const int l15 = lane & 15, l4 = lane >> 4;
  const int qrow0 = qb16*128 + wave*32;
  const float C1 = 0.18033688011112042f;  // 0.125 * log2(e)
  bf16x8 qf[2][2];
  #pragma unroll
  for (int mi = 0; mi < 2; ++mi)
    #pragma unroll
    for (int kh = 0; kh < 2; ++kh)
      qf[mi][kh] = *(const bf16x8*)(qp + (size_t)(qrow0 + mi*16 + l15)*TQKV + kh*32 + l4*8);
  const int srow = lane >> 3;
  const int scol = ((lane & 7) ^ srow) * 8;
  f32x4 o[2][4] = {};
  float rl[2] = {0.0f, 0.0f};
  const int flipw = (l15 & 7) << 3;

  #define STAGE(t, buf) do {                                                     \
    _Pragma("unroll")                                                            \
    for (int i_ = 0; i_ < 2; ++i_) {                                             \
      const int r_ = i_*32 + wave*8;                                             \
      gld_lds16(kp + (size_t)((t)*64 + r_ + srow)*TQKV + scol, &Ks[buf][r_*64]); \
      gld_lds16(vp + (size_t)(r_ + srow)*TS + (t)*64 + scol,   &Vs[buf][r_*64]); \
    }                                                                            \
  } while (0)

  STAGE(0, 0);
  for (int t = 0; t < TS/64; ++t) {
    const int cur = t & 1;
    if (t < TS/64 - 1) {
      STAGE(t+1, cur^1);
      asm volatile("s_waitcnt vmcnt(4)" ::: "memory");
    } else {
      asm volatile("s_waitcnt vmcnt(0)" ::: "memory");
    }
    IRFENCE(); __builtin_amdgcn_s_barrier(); IRFENCE();
    // ---- swapped QK^T, kf streamed per nj (T5: MFMA cluster at prio 1) ----
    f32x4 st[2][4] = {};
    __builtin_amdgcn_s_setprio(1);
    #pragma unroll
    for (int nj = 0; nj < 4; ++nj) {
      const int row = nj*16 + l15;
      const int flip = (row & 7) << 3;
      bf16x8 kf0 = *(const bf16x8*)&Ks[cur][row*64 + ((l4*8) ^ flip)];
      bf16x8 kf1 = *(const bf16x8*)&Ks[cur][row*64 + ((32 + l4*8) ^ flip)];
      st[0][nj] = __builtin_amdgcn_mfma_f32_16x16x32_bf16(kf0, qf[0][0], st[0][nj], 0, 0, 0);
      st[0][nj] = __builtin_amdgcn_mfma_f32_16x16x32_bf16(kf1, qf[0][1], st[0][nj], 0, 0, 0);
      st[1][nj] = __builtin_amdgcn_mfma_f32_16x16x32_bf16(kf0, qf[1][0], st[1][nj], 0, 0, 0);
      st[1][nj] = __builtin_amdgcn_mfma_f32_16x16x32_bf16(kf1, qf[1][1], st[1][nj], 0, 0, 0);
    }
    __builtin_amdgcn_s_setprio(0);
    // ---- per-mi: P = 2^(st*C1) -> pl16 -> pa (in-order DS makes this safe) ----
    bf16x8 pa[2][2];
    #pragma unroll
    for (int mi = 0; mi < 2; ++mi) {
      float rs = 0.0f;
      #pragma unroll
      for (int nj = 0; nj < 4; ++nj) {
        float p0 = fexp2(st[mi][nj][0]*C1);
        float p1 = fexp2(st[mi][nj][1]*C1);
        float p2 = fexp2(st[mi][nj][2]*C1);
        float p3 = fexp2(st[mi][nj][3]*C1);
        rs += (p0+p1)+(p2+p3);
        bf16x4 pk;
        pk[0] = (bf16_t)p0; pk[1] = (bf16_t)p1; pk[2] = (bf16_t)p2; pk[3] = (bf16_t)p3;
        const int colb = (nj*16 + l4*4) ^ flipw;
        *(bf16x4*)(&pl[wave][l15*64 + colb]) = pk;
      }
      rs += __shfl_xor(rs, 16);
      rs += __shfl_xor(rs, 32);
      rl[mi] += rs;
      pa[mi][0] = *(const bf16x8*)&pl[wave][l15*64 + ((l4*8) ^ flipw)];
      pa[mi][1] = *(const bf16x8*)&pl[wave][l15*64 + ((32 + l4*8) ^ flipw)];
    }
    // ---- PV: O += P[32x64] @ V^T, vf streamed per df (T5 prio 1) ----
    __builtin_amdgcn_s_setprio(1);
    #pragma unroll
    for (int df = 0; df < 4; ++df) {
      const int vrow = df*16 + l15;
      const int flip = (vrow & 7) << 3;
      bf16x8 vf0 = *(const bf16x8*)&Vs[cur][vrow*64 + ((l4*8) ^ flip)];
      bf16x8 vf1 = *(const bf16x8*)&Vs[cur][vrow*64 + ((32 + l4*8) ^ flip)];
      o[0][df] = __builtin_amdgcn_mfma_f32_16x16x32_bf16(pa[0][0], vf0, o[0][df], 0, 0, 0);
      o[0][df] = __builtin_amdgcn_mfma_f32_16x16x32_bf16(pa[0][1], vf1, o[0][df], 0, 0, 0);
      o[1][df] = __builtin_amdgcn_mfma_f32_16x16x32_bf16(pa[1][0], vf0, o[1][df], 0, 0, 0);
      o[1][df] = __builtin_amdgcn_mfma_f32_16x16x32_bf16(pa[1][1], vf1, o[1][df], 0, 0, 0);
    }
    __builtin_amdgcn_s_setprio(0);
    IRFENCE(); __builtin_amdgcn_s_barrier(); IRFENCE();  // protect cur before overwrite
  }
  #undef STAGE
  #pragma unroll
  for (int mi = 0; mi < 2; ++mi) {
    const float inv = 1.0f / rl[mi];
    #pragma unroll
    for (int r = 0; r < 4; ++r) {
      const float invr = __shfl(inv, l4*4 + r, 16);
      const size_t rowoff = (size_t)b*TS*TD + (size_t)(qrow0 + mi*16 + l4*4 + r)*TD + h*THD;
      #pragma unroll
      for (int df = 0; df < 4; ++df)
        ((bf16_t*)ctx)[rowoff + df*16 + l15] = (bf16_t)(o[mi][df][r] * invr);
    }
  }
}

extern "C" void kernel_launch(void* const* d_in, const int* in_sizes, int n_in,
                              void* d_out, int out_size, void* d_ws, size_t ws_size,
                              hipStream_t stream) {
  (void)in_sizes; (void)n_in; (void)out_size;
  const int*   ids  = (const int*)  d_in[0];
  const float* emb  = (const float*)d_in[1];
  const float* q_w  = (const float*)d_in[2];
  const float* q_b  = (const float*)d_in[3];
  const float* k_w  = (const float*)d_in[4];
  const float* k_b  = (const float*)d_in[5];
  const float* v_w  = (const float*)d_in[6];
  const float* v_b  = (const float*)d_in[7];
  const float* o_w  = (const float*)d_in[8];
  const float* o_b  = (const float*)d_in[9];
  const float* f1_w = (const float*)d_in[10];
  const float* f1_b = (const float*)d_in[11];
  const float* f2_w = (const float*)d_in[12];
  const float* f2_b = (const float*)d_in[13];
  const float* n1_w = (const float*)d_in[14];
  const float* n1_b = (const float*)d_in[15];
  const float* n2_w = (const float*)d_in[16];
  const float* n2_b = (const float*)d_in[17];
  const float* fn_w = (const float*)d_in[18];
  const float* fn_b = (const float*)d_in[19];

  char* ws = (char*)d_ws;
  size_t off = 0;
  auto alloc = [&](size_t bytes) -> void* {
    void* p = ws + off;
    off += (bytes + 255) & ~(size_t)255;
    return p;
  };
  float*          h    = (float*)         alloc((size_t)TT*TD*4);
  unsigned short* xn   = (unsigned short*)alloc((size_t)TT*TD*2);
  unsigned short* xqkv = (unsigned short*)alloc((size_t)TT*TQKV*2);
  unsigned short* cb   = (unsigned short*)alloc((size_t)TT*TD*2);
  unsigned short* ffb  = (unsigned short*)alloc((size_t)TT*TFF*2);
  unsigned short* cpart= (unsigned short*)alloc((size_t)4*TT*TD*2);
  unsigned short* wqkv = (unsigned short*)alloc((size_t)TL*TQKV*TD*2);
  unsigned short* wot  = (unsigned short*)alloc((size_t)TL*TD*TD*2);
  unsigned short* wf1t = (unsigned short*)alloc((size_t)TL*TD*TFF*2);
  unsigned short* wf2t = (unsigned short*)alloc((size_t)TL*TD*TFF*2);
  unsigned short* embb = (unsigned short*)alloc((size_t)TV*TD*2);
  float*          bqkv = (float*)         alloc((size_t)TL*TQKV*4);
  if (off > ws_size) return;
  bf16_t* vt = (bf16_t*)ffb;   // aliased: used before FF1 writes ffb

  transpose_to_bf16<<<dim3((TD/64)*(TD/64), TL), 256, 0, stream>>>(q_w, wqkv, TD, TD, 0,    (size_t)TQKV*TD);
  transpose_to_bf16<<<dim3((TD/64)*(TD/64), TL), 256, 0, stream>>>(k_w, wqkv, TD, TD, TD,   (size_t)TQKV*TD);
  transpose_to_bf16<<<dim3((TD/64)*(TD/64), TL), 256, 0, stream>>>(v_w, wqkv, TD, TD, 2*TD, (size_t)TQKV*TD);
  transpose_to_bf16<<<dim3((TD/64)*(TD/64), TL), 256, 0, stream>>>(o_w, wot, TD, TD, 0, (size_t)TD*TD);
  transpose_to_bf16<<<dim3((TD/64)*(TFF/64), TL), 256, 0, stream>>>(f1_w, wf1t, TD, TFF, 0, (size_t)TD*TFF);
  transpose_to_bf16<<<dim3((TFF/64)*(TD/64), TL), 256, 0, stream>>>(f2_w, wf2t, TFF, TD, 0, (size_t)TD*TFF);
  pack_qkv_bias<<<TL, TD, 0, stream>>>(q_b, k_b, v_b, bqkv);
  convert_bf16_k<<<(TV*TD)/1024, 256, 0, stream>>>(emb, embb);
  embed_rope<<<TT, 256, 0, stream>>>(ids, emb, h);

  ln_fwd<<<TT, 256, 0, stream>>>(h, n1_w, n1_b, xn);
  for (int lay = 0; lay < TL; ++lay) {
    gemm_bt<4><<<(TT/128)*(TQKV/128), 256, 0, stream>>>((const bf16_t*)xn,
        (const bf16_t*)(wqkv + (size_t)lay*TQKV*TD), bqkv + lay*TQKV, xqkv, vt, TQKV, TD, TQKV/128);
    attn_fwd<<<TB*TH*(TS/128), 256, 0, stream>>>((const bf16_t*)xqkv, vt, cb);
    // O-proj split-K x2 -> bf16 partials; reduce + bias fused into ln2
    gemm_bt<5><<<dim3((TT/128)*(TD/128), 2), 256, 0, stream>>>((const bf16_t*)cb,
        (const bf16_t*)(wot + (size_t)lay*TD*TD), nullptr, cpart, nullptr, TD, TD, TD/128);
    ln_fused<2><<<TT, 256, 0, stream>>>(h, cpart, o_b + lay*TD, n2_w + lay*TD, n2_b + lay*TD, xn);
    gemm_bt<1><<<(TT/128)*(TFF/128), 256, 0, stream>>>((const bf16_t*)xn,
        (const bf16_t*)(wf1t + (size_t)lay*TD*TFF), f1_b + lay*TFF, ffb, nullptr, TFF, TD, TFF/128);
    // FF2 split-K x4 -> bf16 partials; reduce fused into next LN
    gemm_bt<5><<<dim3((TT/128)*(TD/128), 4), 256, 0, stream>>>((const bf16_t*)ffb,
        (const bf16_t*)(wf2t + (size_t)lay*TD*TFF), nullptr, cpart, nullptr, TD, TFF, TD/128);
    if (lay < TL - 1) {
      ln_fused<4><<<TT, 256, 0, stream>>>(h, cpart, f2_b + lay*TD,
          n1_w + (lay+1)*TD, n1_b + (lay+1)*TD, xn);
    } else {
      ln_fused<4><<<TT, 256, 0, stream>>>(h, cpart, f2_b + lay*TD, fn_w, fn_b, xn);
    }
  }
  gemm256<3><<<32*(TV/256), 512, 0, stream>>>((const bf16_t*)xn,
      (const bf16_t*)embb, nullptr, d_out, TV, TD, TV/256);
}